// Round 8
// baseline (1672.331 us; speedup 1.0000x reference)
//
#include <hip/hip_runtime.h>

#define T_LEN 4096
#define C_DIM 2048
#define REC 224          // packed record: 16x[a,b,k,r] bf16 128B | dec/y f32 64B | v bf16 32B
#define CH 64            // scan steps per LDS chunk (64*224 = 14336 B)
#define CHB (CH * REC)

typedef __attribute__((ext_vector_type(4))) float f32x4;
typedef __attribute__((ext_vector_type(2))) float f32x2;
typedef __attribute__((ext_vector_type(8))) __bf16 bf16x8;
typedef __attribute__((ext_vector_type(8))) unsigned short u16x8;
typedef __attribute__((ext_vector_type(4))) unsigned int u32x4;
typedef __attribute__((ext_vector_type(2))) unsigned int u32x2;
typedef unsigned short u16;
typedef unsigned int u32;

typedef __attribute__((address_space(1))) const void* as1cv;
typedef __attribute__((address_space(3))) void* as3v;

__device__ __forceinline__ void gld16(const void* g, void* l) {
  __builtin_amdgcn_global_load_lds((as1cv)g, (as3v)l, 16, 0, 0);
}

__device__ __forceinline__ u16 f2bf(float f) {
  union { float f; unsigned u; } x; x.f = f;
  return (u16)((x.u + 0x7fffu + ((x.u >> 16) & 1u)) >> 16);
}
__device__ __forceinline__ float bflo(unsigned u) {
  union { unsigned u; float f; } x; x.u = u << 16; return x.f;
}
__device__ __forceinline__ float bfhi(unsigned u) {
  union { unsigned u; float f; } x; x.u = u & 0xffff0000u; return x.f;
}
// sum over a 16-lane row via DPP (xor1, xor2, row_ror:4, row_ror:8) — all lanes get the sum
__device__ __forceinline__ float red16(float x) {
  int a;
  a = __builtin_amdgcn_update_dpp(0, __builtin_bit_cast(int, x), 0xB1, 0xF, 0xF, true);
  x += __builtin_bit_cast(float, a);
  a = __builtin_amdgcn_update_dpp(0, __builtin_bit_cast(int, x), 0x4E, 0xF, 0xF, true);
  x += __builtin_bit_cast(float, a);
  a = __builtin_amdgcn_update_dpp(0, __builtin_bit_cast(int, x), 0x124, 0xF, 0xF, true);
  x += __builtin_bit_cast(float, a);
  a = __builtin_amdgcn_update_dpp(0, __builtin_bit_cast(int, x), 0x128, 0xF, 0xF, true);
  x += __builtin_bit_cast(float, a);
  return x;
}
__device__ __forceinline__ f32x4 red16v(f32x4 v) {
  v[0] = red16(v[0]); v[1] = red16(v[1]);
  v[2] = red16(v[2]); v[3] = red16(v[3]);
  return v;
}

// ---------------- weights fp32 -> bf16 (all four in one launch) ----------------
__global__ __launch_bounds__(256)
void conv_bf16_k(const float* __restrict__ s0, const float* __restrict__ s1,
                 const float* __restrict__ s2, const float* __restrict__ s3,
                 u16* __restrict__ d0) {
  const float* s = (blockIdx.y == 0) ? s0 : (blockIdx.y == 1) ? s1
                   : (blockIdx.y == 2) ? s2 : s3;
  u16* d = d0 + (size_t)blockIdx.y * 4194304;
  int i = (blockIdx.x * 256 + threadIdx.x) * 8;
  f32x4 a = *(const f32x4*)(s + i);
  f32x4 b = *(const f32x4*)(s + i + 4);
  u16x8 o;
  o[0] = f2bf(a[0]); o[1] = f2bf(a[1]); o[2] = f2bf(a[2]); o[3] = f2bf(a[3]);
  o[4] = f2bf(b[0]); o[5] = f2bf(b[1]); o[6] = f2bf(b[2]); o[7] = f2bf(b[3]);
  *(u16x8*)(d + i) = o;
}

// ---------------- LoRA-down matrices: (C x 8) -> (8 x C) fp32 transpose ----------------
__global__ __launch_bounds__(256)
void trans_lora_k(const float* __restrict__ w1, const float* __restrict__ a1,
                  const float* __restrict__ v1, const float* __restrict__ g1,
                  float* __restrict__ wt) {
  const float* s = (blockIdx.y == 0) ? w1 : (blockIdx.y == 1) ? a1
                   : (blockIdx.y == 2) ? v1 : g1;
  float* d = wt + (size_t)blockIdx.y * (8 * C_DIM);
  int c = blockIdx.x * 256 + threadIdx.x;    // grid.x = 8
  f32x4 lo = *(const f32x4*)(s + c * 8);
  f32x4 hi = *(const f32x4*)(s + c * 8 + 4);
  d[0 * C_DIM + c] = lo[0]; d[1 * C_DIM + c] = lo[1];
  d[2 * C_DIM + c] = lo[2]; d[3 * C_DIM + c] = lo[3];
  d[4 * C_DIM + c] = hi[0]; d[5 * C_DIM + c] = hi[1];
  d[6 * C_DIM + c] = hi[2]; d[7 * C_DIM + c] = hi[3];
}

// ---------------- mix + LoRA down (strided mapping, all loads coalesced) ----------------
__global__ __launch_bounds__(256)
void mix_lora_k(const float* __restrict__ x,
                const float* __restrict__ xrw, const float* __restrict__ xww,
                const float* __restrict__ xkw, const float* __restrict__ xvw,
                const float* __restrict__ xaw, const float* __restrict__ xgw,
                const float* __restrict__ wt,   // 4 transposed tables, 8xC each
                u16* __restrict__ xr_bf, u16* __restrict__ xk_bf,
                u16* __restrict__ xv_bf, float* __restrict__ lora8) {
  const int rr = blockIdx.x;
  const int t = rr & (T_LEN - 1);
  const int tid = threadIdx.x;
  const float* xrow = x + (size_t)rr * C_DIM;
  float wl[8], al[8], vl[8], gl[8];
  #pragma unroll
  for (int l = 0; l < 8; ++l) { wl[l] = 0.f; al[l] = 0.f; vl[l] = 0.f; gl[l] = 0.f; }
  #pragma unroll
  for (int ii = 0; ii < 8; ++ii) {
    const int c = ii * 256 + tid;
    float xi = xrow[c];
    float xpv = t ? xrow[c - C_DIM] : 0.f;
    float dx = xpv - xi;
    float xr_ = fmaf(dx, xrw[c], xi);
    float xw_ = fmaf(dx, xww[c], xi);
    float xk_ = fmaf(dx, xkw[c], xi);
    float xv_ = fmaf(dx, xvw[c], xi);
    float xa_ = fmaf(dx, xaw[c], xi);
    float xg_ = fmaf(dx, xgw[c], xi);
    xr_bf[(size_t)rr * C_DIM + c] = f2bf(xr_);
    xk_bf[(size_t)rr * C_DIM + c] = f2bf(xk_);
    xv_bf[(size_t)rr * C_DIM + c] = f2bf(xv_);
    #pragma unroll
    for (int l = 0; l < 8; ++l) {
      wl[l] = fmaf(xw_, wt[l * C_DIM + c], wl[l]);
      al[l] = fmaf(xa_, wt[16384 + l * C_DIM + c], al[l]);
      vl[l] = fmaf(xv_, wt[32768 + l * C_DIM + c], vl[l]);
      gl[l] = fmaf(xg_, wt[49152 + l * C_DIM + c], gl[l]);
    }
  }
  // row-reduce (16 lanes) all 32 partials via DPP — pure VALU
  f32x4 w03 = red16v((f32x4){wl[0], wl[1], wl[2], wl[3]});
  f32x4 w47 = red16v((f32x4){wl[4], wl[5], wl[6], wl[7]});
  f32x4 a03 = red16v((f32x4){al[0], al[1], al[2], al[3]});
  f32x4 a47 = red16v((f32x4){al[4], al[5], al[6], al[7]});
  f32x4 v03 = red16v((f32x4){vl[0], vl[1], vl[2], vl[3]});
  f32x4 v47 = red16v((f32x4){vl[4], vl[5], vl[6], vl[7]});
  f32x4 g03 = red16v((f32x4){gl[0], gl[1], gl[2], gl[3]});
  f32x4 g47 = red16v((f32x4){gl[4], gl[5], gl[6], gl[7]});
  __shared__ __attribute__((aligned(16))) float red2[16][32];
  const int row = tid >> 4;          // 16 rows of 16 lanes
  if ((tid & 15) == 0) {
    *(f32x4*)&red2[row][0] = w03;  *(f32x4*)&red2[row][4] = w47;
    *(f32x4*)&red2[row][8] = a03;  *(f32x4*)&red2[row][12] = a47;
    *(f32x4*)&red2[row][16] = v03; *(f32x4*)&red2[row][20] = v47;
    *(f32x4*)&red2[row][24] = g03; *(f32x4*)&red2[row][28] = g47;
  }
  __syncthreads();
  if (tid < 32) {
    float s = 0.f;
    #pragma unroll
    for (int r = 0; r < 16; ++r) s += red2[r][tid];
    int mat = tid >> 3;
    if (mat == 0) s = tanhf(s);
    else if (mat == 3) s = 1.f / (1.f + expf(-s));
    lora8[(size_t)rr * 32 + tid] = s;
  }
}

// ---------------- batched bf16 MFMA GEMM (k/r/v) -> packed scatter ----------------
__global__ __launch_bounds__(256)
void gemm3_k(const u16* __restrict__ xk, const u16* __restrict__ xr,
             const u16* __restrict__ xv, const u16* __restrict__ Wall,
             char* __restrict__ packed) {
  const int z = blockIdx.z;
  const u16* A = (z == 0) ? xk : (z == 1) ? xr : xv;
  const u16* Bw = Wall + (size_t)((z == 0) ? 1 : (z == 1) ? 0 : 2) * 4194304;
  const int sbase = (z == 0) ? 4 : (z == 1) ? 6 : 192;
  const int sstr = (z == 2) ? 2 : 8;
  __shared__ __attribute__((aligned(16))) u16 As[128 * 32];
  __shared__ __attribute__((aligned(16))) u16 Bs[128 * 32];
  const int tid = threadIdx.x;
  const int wv = tid >> 6, ln = tid & 63;
  const int wr = wv >> 1, wc = wv & 1;
  const int row0 = blockIdx.y * 128, col0 = blockIdx.x * 128;
  const int lr = ln & 15, lk = (ln >> 4) << 3;
  f32x4 acc[4][4];
  #pragma unroll
  for (int m = 0; m < 4; ++m)
    #pragma unroll
    for (int n = 0; n < 4; ++n) acc[m][n] = (f32x4){0.f, 0.f, 0.f, 0.f};
  const int e0 = tid * 8;
  const int r0 = e0 >> 5, kofs = e0 & 31;
  for (int kt = 0; kt < 2048; kt += 32) {
    __syncthreads();
    gld16(A + (size_t)(row0 + r0) * 2048 + kt + kofs, As + wv * 512);
    gld16(A + (size_t)(row0 + 64 + r0) * 2048 + kt + kofs, As + 2048 + wv * 512);
    gld16(Bw + (size_t)(col0 + r0) * 2048 + kt + kofs, Bs + wv * 512);
    gld16(Bw + (size_t)(col0 + 64 + r0) * 2048 + kt + kofs, Bs + 2048 + wv * 512);
    __syncthreads();
    bf16x8 af[4], bfr[4];
    #pragma unroll
    for (int m = 0; m < 4; ++m)
      af[m] = *(const bf16x8*)(As + (wr * 64 + m * 16 + lr) * 32 + lk);
    #pragma unroll
    for (int n = 0; n < 4; ++n)
      bfr[n] = *(const bf16x8*)(Bs + (wc * 64 + n * 16 + lr) * 32 + lk);
    #pragma unroll
    for (int m = 0; m < 4; ++m)
      #pragma unroll
      for (int n = 0; n < 4; ++n)
        acc[m][n] = __builtin_amdgcn_mfma_f32_16x16x32_bf16(af[m], bfr[n], acc[m][n], 0, 0, 0);
  }
  const int rowb = row0 + wr * 64 + ((ln >> 4) << 2);
  const int colb = col0 + wc * 64 + (ln & 15);
  #pragma unroll
  for (int m = 0; m < 4; ++m)
    #pragma unroll
    for (int n = 0; n < 4; ++n)
      #pragma unroll
      for (int qq = 0; qq < 4; ++qq) {
        int row = rowb + m * 16 + qq;
        int col = colb + n * 16;
        int bq = row >> 12, tq = row & (T_LEN - 1);
        int hq = col >> 4, jq = col & 15;
        *(u16*)(packed + (size_t)((bq * 128 + hq) * T_LEN + tq) * REC
                + sbase + jq * sstr) = f2bf(acc[m][n][qq]);
      }
}

// ---------------- output bf16 MFMA GEMM: f32 row-major ----------------
__global__ __launch_bounds__(256)
void gemm_k(const u16* __restrict__ A, const u16* __restrict__ Bw,
            float* __restrict__ Co) {
  __shared__ __attribute__((aligned(16))) u16 As[128 * 32];
  __shared__ __attribute__((aligned(16))) u16 Bs[128 * 32];
  const int tid = threadIdx.x;
  const int wv = tid >> 6, ln = tid & 63;
  const int wr = wv >> 1, wc = wv & 1;
  const int row0 = blockIdx.y * 128, col0 = blockIdx.x * 128;
  const int lr = ln & 15, lk = (ln >> 4) << 3;
  f32x4 acc[4][4];
  #pragma unroll
  for (int m = 0; m < 4; ++m)
    #pragma unroll
    for (int n = 0; n < 4; ++n) acc[m][n] = (f32x4){0.f, 0.f, 0.f, 0.f};
  const int e0 = tid * 8;
  const int r0 = e0 >> 5, kofs = e0 & 31;
  for (int kt = 0; kt < 2048; kt += 32) {
    __syncthreads();
    gld16(A + (size_t)(row0 + r0) * 2048 + kt + kofs, As + wv * 512);
    gld16(A + (size_t)(row0 + 64 + r0) * 2048 + kt + kofs, As + 2048 + wv * 512);
    gld16(Bw + (size_t)(col0 + r0) * 2048 + kt + kofs, Bs + wv * 512);
    gld16(Bw + (size_t)(col0 + 64 + r0) * 2048 + kt + kofs, Bs + 2048 + wv * 512);
    __syncthreads();
    bf16x8 af[4], bfr[4];
    #pragma unroll
    for (int m = 0; m < 4; ++m)
      af[m] = *(const bf16x8*)(As + (wr * 64 + m * 16 + lr) * 32 + lk);
    #pragma unroll
    for (int n = 0; n < 4; ++n)
      bfr[n] = *(const bf16x8*)(Bs + (wc * 64 + n * 16 + lr) * 32 + lk);
    #pragma unroll
    for (int m = 0; m < 4; ++m)
      #pragma unroll
      for (int n = 0; n < 4; ++n)
        acc[m][n] = __builtin_amdgcn_mfma_f32_16x16x32_bf16(af[m], bfr[n], acc[m][n], 0, 0, 0);
  }
  const int rowb = row0 + wr * 64 + ((ln >> 4) << 2);
  const int colb = col0 + wc * 64 + (ln & 15);
  #pragma unroll
  for (int m = 0; m < 4; ++m)
    #pragma unroll
    for (int n = 0; n < 4; ++n)
      #pragma unroll
      for (int qq = 0; qq < 4; ++qq)
        Co[(size_t)(rowb + m * 16 + qq) * 2048 + colb + n * 16] = acc[m][n][qq];
}

// ---------------- post-GEMM: LoRA-up, decay, v-mix, kk-norm -> packed ----------------
__global__ __launch_bounds__(256)
void post_gemm_k(const float* __restrict__ v_first, const float* __restrict__ lora8,
                 const float* __restrict__ w0, const float* __restrict__ w2,
                 const float* __restrict__ a0, const float* __restrict__ a2,
                 const float* __restrict__ v0, const float* __restrict__ v2,
                 const float* __restrict__ k_k, const float* __restrict__ k_a,
                 char* __restrict__ packed) {
  const int rr = blockIdx.x;
  const int bq = rr >> 12, tq = rr & (T_LEN - 1);
  const int tid = threadIdx.x, c0 = tid * 8;
  const int hq = tid >> 1, j0 = (tid & 1) * 8;
  char* pb = packed + (size_t)((bq * 128 + hq) * T_LEN + tq) * REC;
  // load 8 j-packets (64 B): word {2m+1} holds [k | r]
  u32x4 pk0 = *(const u32x4*)(pb + j0 * 8);
  u32x4 pk1 = *(const u32x4*)(pb + j0 * 8 + 16);
  u32x4 pk2 = *(const u32x4*)(pb + j0 * 8 + 32);
  u32x4 pk3 = *(const u32x4*)(pb + j0 * 8 + 48);
  u32x4 uv = *(const u32x4*)(pb + 192 + 2 * j0);
  float kraw[8], vraw[8];
  kraw[0] = bflo(pk0[1]); kraw[1] = bflo(pk0[3]);
  kraw[2] = bflo(pk1[1]); kraw[3] = bflo(pk1[3]);
  kraw[4] = bflo(pk2[1]); kraw[5] = bflo(pk2[3]);
  kraw[6] = bflo(pk3[1]); kraw[7] = bflo(pk3[3]);
  #pragma unroll
  for (int ii = 0; ii < 4; ++ii) {
    vraw[2 * ii] = bflo(uv[ii]); vraw[2 * ii + 1] = bfhi(uv[ii]);
  }
  float vf[8] __attribute__((aligned(16)));
  const float* vfp = v_first + (size_t)rr * C_DIM + c0;
  *(f32x4*)vf = *(const f32x4*)vfp;
  *(f32x4*)(vf + 4) = *(const f32x4*)(vfp + 4);
  const float* lo = lora8 + (size_t)rr * 32;
  float w8[8] __attribute__((aligned(16)));
  float a8[8] __attribute__((aligned(16)));
  float v8[8] __attribute__((aligned(16)));
  *(f32x4*)w8 = *(const f32x4*)lo;        *(f32x4*)(w8 + 4) = *(const f32x4*)(lo + 4);
  *(f32x4*)a8 = *(const f32x4*)(lo + 8);  *(f32x4*)(a8 + 4) = *(const f32x4*)(lo + 12);
  *(f32x4*)v8 = *(const f32x4*)(lo + 16); *(f32x4*)(v8 + 4) = *(const f32x4*)(lo + 20);
  float kk[8], av[8];
  float dec[8] __attribute__((aligned(16)));
  u16 wk[8];
  u16x8 wv2;
  float ss = 0.f;
  #pragma unroll
  for (int ii = 0; ii < 8; ++ii) {
    int c = c0 + ii;
    float wr_ = w0[c], ar_ = a0[c], vr_ = v0[c];
    #pragma unroll
    for (int l = 0; l < 8; ++l) {
      wr_ = fmaf(w8[l], w2[(size_t)l * C_DIM + c], wr_);
      ar_ = fmaf(a8[l], a2[(size_t)l * C_DIM + c], ar_);
      vr_ = fmaf(v8[l], v2[(size_t)l * C_DIM + c], vr_);
    }
    float w_ = -log1pf(expf(-wr_)) - 0.5f;
    dec[ii] = expf(-expf(w_));
    float a_ = 1.f / (1.f + expf(-ar_));
    float vm = 1.f / (1.f + expf(-vr_));
    wv2[ii] = f2bf(fmaf(vf[ii] - vraw[ii], vm, vraw[ii]));
    kk[ii] = kraw[ii] * k_k[c];
    ss = fmaf(kk[ii], kk[ii], ss);
    av[ii] = a_;
    wk[ii] = f2bf(kraw[ii] * fmaf(a_ - 1.f, k_a[c], 1.f));
  }
  ss += __shfl_xor(ss, 1);
  ss += __shfl_xor(ss, 2);
  ss += __shfl_xor(ss, 4);
  float sc = 1.f / fmaxf(sqrtf(ss), 1e-8f);
  u16 wa[8], wb[8];
  #pragma unroll
  for (int ii = 0; ii < 8; ++ii) {
    float kn = kk[ii] * sc;
    wa[ii] = f2bf(-kn);
    wb[ii] = f2bf(kn * av[ii]);
  }
  // rebuild packets: word0 = a|b<<16, word1 = k | (old r hi16)
  u32x4 o0, o1, o2, o3;
  o0[0] = (u32)wa[0] | ((u32)wb[0] << 16); o0[1] = (u32)wk[0] | (pk0[1] & 0xffff0000u);
  o0[2] = (u32)wa[1] | ((u32)wb[1] << 16); o0[3] = (u32)wk[1] | (pk0[3] & 0xffff0000u);
  o1[0] = (u32)wa[2] | ((u32)wb[2] << 16); o1[1] = (u32)wk[2] | (pk1[1] & 0xffff0000u);
  o1[2] = (u32)wa[3] | ((u32)wb[3] << 16); o1[3] = (u32)wk[3] | (pk1[3] & 0xffff0000u);
  o2[0] = (u32)wa[4] | ((u32)wb[4] << 16); o2[1] = (u32)wk[4] | (pk2[1] & 0xffff0000u);
  o2[2] = (u32)wa[5] | ((u32)wb[5] << 16); o2[3] = (u32)wk[5] | (pk2[3] & 0xffff0000u);
  o3[0] = (u32)wa[6] | ((u32)wb[6] << 16); o3[1] = (u32)wk[6] | (pk3[1] & 0xffff0000u);
  o3[2] = (u32)wa[7] | ((u32)wb[7] << 16); o3[3] = (u32)wk[7] | (pk3[3] & 0xffff0000u);
  *(u32x4*)(pb + j0 * 8) = o0;
  *(u32x4*)(pb + j0 * 8 + 16) = o1;
  *(u32x4*)(pb + j0 * 8 + 32) = o2;
  *(u32x4*)(pb + j0 * 8 + 48) = o3;
  *(u16x8*)(pb + 192 + 2 * j0) = wv2;
  *(f32x4*)(pb + 128 + 4 * j0) = *(f32x4*)dec;
  *(f32x4*)(pb + 128 + 4 * j0 + 16) = *(f32x4*)(dec + 4);
}

// ---------------- sequential RWKV7 scan: 1 head / 2-wave block, 2 rows per lane ----------------
// Two independent recurrence chains per lane (rows r0, r0+1) interleave to hide
// DPP/LDS latency; 2-deep register pipeline over the LDS chunk.
__device__ __forceinline__ void stage2(const char* g, char* l, int wv, int ln) {
  #pragma unroll
  for (int j2 = 0; j2 < 7; ++j2)
    gld16(g + j2 * 2048 + wv * 1024 + ln * 16, l + j2 * 2048 + wv * 1024);
}

__global__ __launch_bounds__(128)
void scan_k(char* __restrict__ packed) {
  // 2 chunk halves + 1 KB pad so tail prefetch over-reads stay in-bounds
  __shared__ __attribute__((aligned(16))) char bufm[2 * CHB + 1024];
  const int hb = blockIdx.x;
  const int tid = threadIdx.x;
  const int wv = tid >> 6, ln = tid & 63;
  const int j = ln & 15;
  const int r0 = wv * 8 + 2 * (ln >> 4);   // even row; this lane also owns r0+1
  char* src = packed + (size_t)hb * (T_LEN * REC);
  float S0 = 0.f, S1 = 0.f;
  stage2(src, bufm, wv, ln);
  const int NC = T_LEN / CH;
  for (int c = 0; c < NC; ++c) {
    asm volatile("s_waitcnt vmcnt(0)" ::: "memory");
    __syncthreads();
    if (c + 1 < NC)
      stage2(src + (size_t)(c + 1) * CHB, bufm + ((c + 1) & 1) * CHB, wv, ln);
    const char* Bp = bufm + (c & 1) * CHB;
    float* yg = (float*)(src + (size_t)c * CHB);
    const char* p0 = Bp + j * 8;         // [a|b][k|r] packet, +t*REC
    const char* pd = Bp + 128 + j * 4;   // dec f32
    const char* pv = Bp + 192 + r0 * 2;  // v bf16 pair (r0 even -> 4B aligned)
    // preload steps 0,1
    u32x2 kA = *(const u32x2*)(p0);
    float dA = *(const float*)(pd);
    u32 vA = *(const u32*)(pv);
    u32x2 kB = *(const u32x2*)(p0 + REC);
    float dB = *(const float*)(pd + REC);
    u32 vB = *(const u32*)(pv + REC);
    for (int t = 0; t < CH; t += 2) {
      // prefetch t+2 (over-reads land in pad, discarded at chunk restart)
      u32x2 nkA = *(const u32x2*)(p0 + (t + 2) * REC);
      float ndA = *(const float*)(pd + (t + 2) * REC);
      u32 nvA = *(const u32*)(pv + (t + 2) * REC);
      {
        float a_ = bflo(kA[0]), b_ = bfhi(kA[0]);
        float k_ = bflo(kA[1]), r_ = bfhi(kA[1]);
        float v0_ = bflo(vA), v1_ = bfhi(vA);
        float s0 = red16(S0 * a_);
        float s1 = red16(S1 * a_);
        S0 = fmaf(S0, dA, fmaf(s0, b_, v0_ * k_));
        S1 = fmaf(S1, dA, fmaf(s1, b_, v1_ * k_));
        float y0 = red16(S0 * r_);
        float y1 = red16(S1 * r_);
        if (j == 0) {
          f32x2 yy; yy[0] = y0; yy[1] = y1;
          *(f32x2*)(yg + t * (REC / 4) + 32 + r0) = yy;
        }
      }
      kA = nkA; dA = ndA; vA = nvA;
      // prefetch t+3
      u32x2 nkB = *(const u32x2*)(p0 + (t + 3) * REC);
      float ndB = *(const float*)(pd + (t + 3) * REC);
      u32 nvB = *(const u32*)(pv + (t + 3) * REC);
      {
        float a_ = bflo(kB[0]), b_ = bfhi(kB[0]);
        float k_ = bflo(kB[1]), r_ = bfhi(kB[1]);
        float v0_ = bflo(vB), v1_ = bfhi(vB);
        float s0 = red16(S0 * a_);
        float s1 = red16(S1 * a_);
        S0 = fmaf(S0, dB, fmaf(s0, b_, v0_ * k_));
        S1 = fmaf(S1, dB, fmaf(s1, b_, v1_ * k_));
        float y0 = red16(S0 * r_);
        float y1 = red16(S1 * r_);
        if (j == 0) {
          f32x2 yy; yy[0] = y0; yy[1] = y1;
          *(f32x2*)(yg + (t + 1) * (REC / 4) + 32 + r0) = yy;
        }
      }
      kB = nkB; dB = ndB; vB = nvB;
    }
  }
}

// ---------------- GroupNorm + residual + gate -> bf16 ----------------
__global__ __launch_bounds__(256)
void post_gn_k(const char* __restrict__ packed, const float* __restrict__ lora8,
               const float* __restrict__ g2, const float* __restrict__ ln_g,
               const float* __restrict__ ln_b, const float* __restrict__ r_k,
               u16* __restrict__ og) {
  const int rr = blockIdx.x;
  const int bq = rr >> 12, tq = rr & (T_LEN - 1);
  const int tid = threadIdx.x, c0 = tid * 8;
  const int hq = tid >> 1, j0 = (tid & 1) * 8;
  const char* pb = packed + (size_t)((bq * 128 + hq) * T_LEN + tq) * REC;
  float rv[8], kv[8], vv[8];
  u32x4 pk0 = *(const u32x4*)(pb + j0 * 8);
  u32x4 pk1 = *(const u32x4*)(pb + j0 * 8 + 16);
  u32x4 pk2 = *(const u32x4*)(pb + j0 * 8 + 32);
  u32x4 pk3 = *(const u32x4*)(pb + j0 * 8 + 48);
  kv[0] = bflo(pk0[1]); rv[0] = bfhi(pk0[1]); kv[1] = bflo(pk0[3]); rv[1] = bfhi(pk0[3]);
  kv[2] = bflo(pk1[1]); rv[2] = bfhi(pk1[1]); kv[3] = bflo(pk1[3]); rv[3] = bfhi(pk1[3]);
  kv[4] = bflo(pk2[1]); rv[4] = bfhi(pk2[1]); kv[5] = bflo(pk2[3]); rv[5] = bfhi(pk2[3]);
  kv[6] = bflo(pk3[1]); rv[6] = bfhi(pk3[1]); kv[7] = bflo(pk3[3]); rv[7] = bfhi(pk3[3]);
  u32x4 uv = *(const u32x4*)(pb + 192 + 2 * j0);
  #pragma unroll
  for (int ii = 0; ii < 4; ++ii) {
    vv[2 * ii] = bflo(uv[ii]); vv[2 * ii + 1] = bfhi(uv[ii]);
  }
  f32x4 y0 = *(const f32x4*)(pb + 128 + 4 * j0);
  f32x4 y1 = *(const f32x4*)(pb + 128 + 4 * j0 + 16);
  float o[8];
  o[0] = y0[0]; o[1] = y0[1]; o[2] = y0[2]; o[3] = y0[3];
  o[4] = y1[0]; o[5] = y1[1]; o[6] = y1[2]; o[7] = y1[3];
  float g8[8] __attribute__((aligned(16)));
  const float* lo = lora8 + (size_t)rr * 32 + 24;
  *(f32x4*)g8 = *(const f32x4*)lo;
  *(f32x4*)(g8 + 4) = *(const f32x4*)(lo + 4);
  float s1 = 0.f, s2 = 0.f, srk = 0.f;
  #pragma unroll
  for (int ii = 0; ii < 8; ++ii) {
    s1 += o[ii];
    s2 = fmaf(o[ii], o[ii], s2);
    srk = fmaf(rv[ii] * kv[ii], r_k[c0 + ii], srk);
  }
  s1 += __shfl_xor(s1, 1); s1 += __shfl_xor(s1, 2); s1 += __shfl_xor(s1, 4);
  s2 += __shfl_xor(s2, 1); s2 += __shfl_xor(s2, 2); s2 += __shfl_xor(s2, 4);
  srk += __shfl_xor(srk, 1); srk += __shfl_xor(srk, 2); srk += __shfl_xor(srk, 4);
  float mu = s1 * (1.f / 64.f);
  float var = s2 * (1.f / 64.f) - mu * mu;
  float rstd = rsqrtf(var + 0.00064f);
  u16x8 ov;
  #pragma unroll
  for (int ii = 0; ii < 8; ++ii) {
    int c = c0 + ii;
    float on = fmaf((o[ii] - mu) * rstd, ln_g[c], ln_b[c]);
    float o2 = fmaf(srk, vv[ii], on);
    float gg = 0.f;
    #pragma unroll
    for (int l = 0; l < 8; ++l) gg = fmaf(g8[l], g2[(size_t)l * C_DIM + c], gg);
    ov[ii] = f2bf(o2 * gg);
  }
  *(u16x8*)(og + (size_t)rr * C_DIM + c0) = ov;
}

extern "C" void kernel_launch(void* const* d_in, const int* in_sizes, int n_in,
                              void* d_out, int out_size, void* d_ws, size_t ws_size,
                              hipStream_t stream) {
  (void)in_sizes; (void)n_in; (void)out_size;
  const float* x      = (const float*)d_in[0];
  const float* v_first= (const float*)d_in[1];
  const float* x_r    = (const float*)d_in[2];
  const float* x_w    = (const float*)d_in[3];
  const float* x_k    = (const float*)d_in[4];
  const float* x_v    = (const float*)d_in[5];
  const float* x_a    = (const float*)d_in[6];
  const float* x_g    = (const float*)d_in[7];
  const float* w0     = (const float*)d_in[8];
  const float* w1     = (const float*)d_in[9];
  const float* w2     = (const float*)d_in[10];
  const float* a0     = (const float*)d_in[11];
  const float* a1     = (const float*)d_in[12];
  const float* a2     = (const float*)d_in[13];
  const float* v0     = (const float*)d_in[14];
  const float* v1     = (const float*)d_in[15];
  const float* v2     = (const float*)d_in[16];
  const float* g1     = (const float*)d_in[17];
  const float* g2     = (const float*)d_in[18];
  const float* k_k    = (const float*)d_in[19];
  const float* k_a    = (const float*)d_in[20];
  const float* r_k    = (const float*)d_in[21];
  const float* Wr     = (const float*)d_in[22];
  const float* Wk     = (const float*)d_in[23];
  const float* Wv     = (const float*)d_in[24];
  const float* Wo     = (const float*)d_in[25];
  const float* ln_g   = (const float*)d_in[26];
  const float* ln_b   = (const float*)d_in[27];

  if (ws_size < 370147328ull) return;
  char* ws = (char*)d_ws;
  u16* Wr_bf = (u16*)(ws + 0);            //  8 MB each, contiguous (conv indexes)
  u16* Wo_bf = Wr_bf + 3 * 4194304;
  u16* xr_bf = (u16*)(ws + 33554432);     // 32 MB each
  u16* xk_bf = xr_bf + 16777216;
  u16* xv_bf = xk_bf + 16777216;
  float* lora8 = (float*)(ws + 134217728); // 1 MB
  char* packed = ws + 135266304;           // 224 MB
  float* wt = (float*)packed;              // transposed LoRA tables (256 KB),
                                           // consumed before gemms overwrite
  u16* og = xr_bf;                         // reuse (dead after r-GEMM)
  float* out = (float*)d_out;

  conv_bf16_k<<<dim3(2048, 4), 256, 0, stream>>>(Wr, Wk, Wv, Wo, Wr_bf);
  trans_lora_k<<<dim3(8, 4), 256, 0, stream>>>(w1, a1, v1, g1, wt);

  mix_lora_k<<<8192, 256, 0, stream>>>(x, x_r, x_w, x_k, x_v, x_a, x_g,
                                       wt, xr_bf, xk_bf, xv_bf, lora8);

  gemm3_k<<<dim3(16, 64, 3), 256, 0, stream>>>(xk_bf, xr_bf, xv_bf,
                                               Wr_bf, packed);

  post_gemm_k<<<8192, 256, 0, stream>>>(v_first, lora8, w0, w2, a0, a2, v0, v2,
                                        k_k, k_a, packed);

  scan_k<<<256, 128, 0, stream>>>(packed);

  post_gn_k<<<8192, 256, 0, stream>>>(packed, lora8, g2, ln_g, ln_b, r_k, og);

  gemm_k<<<dim3(16, 64), 256, 0, stream>>>(og, Wo_bf, out);

  hipMemcpyAsync(out + 16777216, v_first, (size_t)16777216 * 4,
                 hipMemcpyDeviceToDevice, stream);
}

// Round 9
// 1449.129 us; speedup vs baseline: 1.1540x; 1.1540x over previous
//
#include <hip/hip_runtime.h>

#define T_LEN 4096
#define C_DIM 2048
#define REC 224          // packed record: 16x[a,b,k,r] bf16 128B | dec/y f32 64B | v bf16 32B
#define CH 64            // scan steps per LDS chunk (64*224 = 14336 B)
#define CHB (CH * REC)

typedef __attribute__((ext_vector_type(4))) float f32x4;
typedef __attribute__((ext_vector_type(8))) __bf16 bf16x8;
typedef __attribute__((ext_vector_type(8))) unsigned short u16x8;
typedef __attribute__((ext_vector_type(4))) unsigned int u32x4;
typedef __attribute__((ext_vector_type(2))) unsigned int u32x2;
typedef unsigned short u16;
typedef unsigned int u32;

typedef __attribute__((address_space(1))) const void* as1cv;
typedef __attribute__((address_space(3))) void* as3v;

__device__ __forceinline__ void gld16(const void* g, void* l) {
  __builtin_amdgcn_global_load_lds((as1cv)g, (as3v)l, 16, 0, 0);
}

__device__ __forceinline__ u16 f2bf(float f) {
  union { float f; unsigned u; } x; x.f = f;
  return (u16)((x.u + 0x7fffu + ((x.u >> 16) & 1u)) >> 16);
}
__device__ __forceinline__ float bflo(unsigned u) {
  union { unsigned u; float f; } x; x.u = u << 16; return x.f;
}
__device__ __forceinline__ float bfhi(unsigned u) {
  union { unsigned u; float f; } x; x.u = u & 0xffff0000u; return x.f;
}
// sum over a 16-lane row via DPP (xor1, xor2, row_ror:4, row_ror:8) — all lanes get the sum
__device__ __forceinline__ float red16(float x) {
  int a;
  a = __builtin_amdgcn_update_dpp(0, __builtin_bit_cast(int, x), 0xB1, 0xF, 0xF, true);
  x += __builtin_bit_cast(float, a);
  a = __builtin_amdgcn_update_dpp(0, __builtin_bit_cast(int, x), 0x4E, 0xF, 0xF, true);
  x += __builtin_bit_cast(float, a);
  a = __builtin_amdgcn_update_dpp(0, __builtin_bit_cast(int, x), 0x124, 0xF, 0xF, true);
  x += __builtin_bit_cast(float, a);
  a = __builtin_amdgcn_update_dpp(0, __builtin_bit_cast(int, x), 0x128, 0xF, 0xF, true);
  x += __builtin_bit_cast(float, a);
  return x;
}
__device__ __forceinline__ f32x4 red16v(f32x4 v) {
  v[0] = red16(v[0]); v[1] = red16(v[1]);
  v[2] = red16(v[2]); v[3] = red16(v[3]);
  return v;
}

// ---------------- weights fp32 -> bf16 (all four in one launch) ----------------
__global__ __launch_bounds__(256)
void conv_bf16_k(const float* __restrict__ s0, const float* __restrict__ s1,
                 const float* __restrict__ s2, const float* __restrict__ s3,
                 u16* __restrict__ d0) {
  const float* s = (blockIdx.y == 0) ? s0 : (blockIdx.y == 1) ? s1
                   : (blockIdx.y == 2) ? s2 : s3;
  u16* d = d0 + (size_t)blockIdx.y * 4194304;
  int i = (blockIdx.x * 256 + threadIdx.x) * 8;
  f32x4 a = *(const f32x4*)(s + i);
  f32x4 b = *(const f32x4*)(s + i + 4);
  u16x8 o;
  o[0] = f2bf(a[0]); o[1] = f2bf(a[1]); o[2] = f2bf(a[2]); o[3] = f2bf(a[3]);
  o[4] = f2bf(b[0]); o[5] = f2bf(b[1]); o[6] = f2bf(b[2]); o[7] = f2bf(b[3]);
  *(u16x8*)(d + i) = o;
}

// ---------------- LoRA-down matrices: (C x 8) -> (8 x C) fp32 transpose ----------------
__global__ __launch_bounds__(256)
void trans_lora_k(const float* __restrict__ w1, const float* __restrict__ a1,
                  const float* __restrict__ v1, const float* __restrict__ g1,
                  float* __restrict__ wt) {
  const float* s = (blockIdx.y == 0) ? w1 : (blockIdx.y == 1) ? a1
                   : (blockIdx.y == 2) ? v1 : g1;
  float* d = wt + (size_t)blockIdx.y * (8 * C_DIM);
  int c = blockIdx.x * 256 + threadIdx.x;    // grid.x = 8
  f32x4 lo = *(const f32x4*)(s + c * 8);
  f32x4 hi = *(const f32x4*)(s + c * 8 + 4);
  d[0 * C_DIM + c] = lo[0]; d[1 * C_DIM + c] = lo[1];
  d[2 * C_DIM + c] = lo[2]; d[3 * C_DIM + c] = lo[3];
  d[4 * C_DIM + c] = hi[0]; d[5 * C_DIM + c] = hi[1];
  d[6 * C_DIM + c] = hi[2]; d[7 * C_DIM + c] = hi[3];
}

// ---------------- mix + LoRA down (strided mapping, all loads coalesced) ----------------
__global__ __launch_bounds__(256)
void mix_lora_k(const float* __restrict__ x,
                const float* __restrict__ xrw, const float* __restrict__ xww,
                const float* __restrict__ xkw, const float* __restrict__ xvw,
                const float* __restrict__ xaw, const float* __restrict__ xgw,
                const float* __restrict__ wt,   // 4 transposed tables, 8xC each
                u16* __restrict__ xr_bf, u16* __restrict__ xk_bf,
                u16* __restrict__ xv_bf, float* __restrict__ lora8) {
  const int rr = blockIdx.x;
  const int t = rr & (T_LEN - 1);
  const int tid = threadIdx.x;
  const float* xrow = x + (size_t)rr * C_DIM;
  float wl[8], al[8], vl[8], gl[8];
  #pragma unroll
  for (int l = 0; l < 8; ++l) { wl[l] = 0.f; al[l] = 0.f; vl[l] = 0.f; gl[l] = 0.f; }
  #pragma unroll
  for (int ii = 0; ii < 8; ++ii) {
    const int c = ii * 256 + tid;
    float xi = xrow[c];
    float xpv = t ? xrow[c - C_DIM] : 0.f;
    float dx = xpv - xi;
    float xr_ = fmaf(dx, xrw[c], xi);
    float xw_ = fmaf(dx, xww[c], xi);
    float xk_ = fmaf(dx, xkw[c], xi);
    float xv_ = fmaf(dx, xvw[c], xi);
    float xa_ = fmaf(dx, xaw[c], xi);
    float xg_ = fmaf(dx, xgw[c], xi);
    xr_bf[(size_t)rr * C_DIM + c] = f2bf(xr_);
    xk_bf[(size_t)rr * C_DIM + c] = f2bf(xk_);
    xv_bf[(size_t)rr * C_DIM + c] = f2bf(xv_);
    #pragma unroll
    for (int l = 0; l < 8; ++l) {
      wl[l] = fmaf(xw_, wt[l * C_DIM + c], wl[l]);
      al[l] = fmaf(xa_, wt[16384 + l * C_DIM + c], al[l]);
      vl[l] = fmaf(xv_, wt[32768 + l * C_DIM + c], vl[l]);
      gl[l] = fmaf(xg_, wt[49152 + l * C_DIM + c], gl[l]);
    }
  }
  // row-reduce (16 lanes) all 32 partials via DPP — pure VALU
  f32x4 w03 = red16v((f32x4){wl[0], wl[1], wl[2], wl[3]});
  f32x4 w47 = red16v((f32x4){wl[4], wl[5], wl[6], wl[7]});
  f32x4 a03 = red16v((f32x4){al[0], al[1], al[2], al[3]});
  f32x4 a47 = red16v((f32x4){al[4], al[5], al[6], al[7]});
  f32x4 v03 = red16v((f32x4){vl[0], vl[1], vl[2], vl[3]});
  f32x4 v47 = red16v((f32x4){vl[4], vl[5], vl[6], vl[7]});
  f32x4 g03 = red16v((f32x4){gl[0], gl[1], gl[2], gl[3]});
  f32x4 g47 = red16v((f32x4){gl[4], gl[5], gl[6], gl[7]});
  __shared__ __attribute__((aligned(16))) float red2[16][32];
  const int row = tid >> 4;          // 16 rows of 16 lanes
  if ((tid & 15) == 0) {
    *(f32x4*)&red2[row][0] = w03;  *(f32x4*)&red2[row][4] = w47;
    *(f32x4*)&red2[row][8] = a03;  *(f32x4*)&red2[row][12] = a47;
    *(f32x4*)&red2[row][16] = v03; *(f32x4*)&red2[row][20] = v47;
    *(f32x4*)&red2[row][24] = g03; *(f32x4*)&red2[row][28] = g47;
  }
  __syncthreads();
  if (tid < 32) {
    float s = 0.f;
    #pragma unroll
    for (int r = 0; r < 16; ++r) s += red2[r][tid];
    int mat = tid >> 3;
    if (mat == 0) s = tanhf(s);
    else if (mat == 3) s = 1.f / (1.f + expf(-s));
    lora8[(size_t)rr * 32 + tid] = s;
  }
}

// ---------------- batched bf16 MFMA GEMM (k/r/v) -> packed scatter ----------------
__global__ __launch_bounds__(256)
void gemm3_k(const u16* __restrict__ xk, const u16* __restrict__ xr,
             const u16* __restrict__ xv, const u16* __restrict__ Wall,
             char* __restrict__ packed) {
  const int z = blockIdx.z;
  const u16* A = (z == 0) ? xk : (z == 1) ? xr : xv;
  const u16* Bw = Wall + (size_t)((z == 0) ? 1 : (z == 1) ? 0 : 2) * 4194304;
  const int sbase = (z == 0) ? 4 : (z == 1) ? 6 : 192;
  const int sstr = (z == 2) ? 2 : 8;
  __shared__ __attribute__((aligned(16))) u16 As[128 * 32];
  __shared__ __attribute__((aligned(16))) u16 Bs[128 * 32];
  const int tid = threadIdx.x;
  const int wv = tid >> 6, ln = tid & 63;
  const int wr = wv >> 1, wc = wv & 1;
  const int row0 = blockIdx.y * 128, col0 = blockIdx.x * 128;
  const int lr = ln & 15, lk = (ln >> 4) << 3;
  f32x4 acc[4][4];
  #pragma unroll
  for (int m = 0; m < 4; ++m)
    #pragma unroll
    for (int n = 0; n < 4; ++n) acc[m][n] = (f32x4){0.f, 0.f, 0.f, 0.f};
  const int e0 = tid * 8;
  const int r0 = e0 >> 5, kofs = e0 & 31;
  for (int kt = 0; kt < 2048; kt += 32) {
    __syncthreads();
    gld16(A + (size_t)(row0 + r0) * 2048 + kt + kofs, As + wv * 512);
    gld16(A + (size_t)(row0 + 64 + r0) * 2048 + kt + kofs, As + 2048 + wv * 512);
    gld16(Bw + (size_t)(col0 + r0) * 2048 + kt + kofs, Bs + wv * 512);
    gld16(Bw + (size_t)(col0 + 64 + r0) * 2048 + kt + kofs, Bs + 2048 + wv * 512);
    __syncthreads();
    bf16x8 af[4], bfr[4];
    #pragma unroll
    for (int m = 0; m < 4; ++m)
      af[m] = *(const bf16x8*)(As + (wr * 64 + m * 16 + lr) * 32 + lk);
    #pragma unroll
    for (int n = 0; n < 4; ++n)
      bfr[n] = *(const bf16x8*)(Bs + (wc * 64 + n * 16 + lr) * 32 + lk);
    #pragma unroll
    for (int m = 0; m < 4; ++m)
      #pragma unroll
      for (int n = 0; n < 4; ++n)
        acc[m][n] = __builtin_amdgcn_mfma_f32_16x16x32_bf16(af[m], bfr[n], acc[m][n], 0, 0, 0);
  }
  const int rowb = row0 + wr * 64 + ((ln >> 4) << 2);
  const int colb = col0 + wc * 64 + (ln & 15);
  #pragma unroll
  for (int m = 0; m < 4; ++m)
    #pragma unroll
    for (int n = 0; n < 4; ++n)
      #pragma unroll
      for (int qq = 0; qq < 4; ++qq) {
        int row = rowb + m * 16 + qq;
        int col = colb + n * 16;
        int bq = row >> 12, tq = row & (T_LEN - 1);
        int hq = col >> 4, jq = col & 15;
        *(u16*)(packed + (size_t)((bq * 128 + hq) * T_LEN + tq) * REC
                + sbase + jq * sstr) = f2bf(acc[m][n][qq]);
      }
}

// ---------------- output bf16 MFMA GEMM: f32 row-major ----------------
__global__ __launch_bounds__(256)
void gemm_k(const u16* __restrict__ A, const u16* __restrict__ Bw,
            float* __restrict__ Co) {
  __shared__ __attribute__((aligned(16))) u16 As[128 * 32];
  __shared__ __attribute__((aligned(16))) u16 Bs[128 * 32];
  const int tid = threadIdx.x;
  const int wv = tid >> 6, ln = tid & 63;
  const int wr = wv >> 1, wc = wv & 1;
  const int row0 = blockIdx.y * 128, col0 = blockIdx.x * 128;
  const int lr = ln & 15, lk = (ln >> 4) << 3;
  f32x4 acc[4][4];
  #pragma unroll
  for (int m = 0; m < 4; ++m)
    #pragma unroll
    for (int n = 0; n < 4; ++n) acc[m][n] = (f32x4){0.f, 0.f, 0.f, 0.f};
  const int e0 = tid * 8;
  const int r0 = e0 >> 5, kofs = e0 & 31;
  for (int kt = 0; kt < 2048; kt += 32) {
    __syncthreads();
    gld16(A + (size_t)(row0 + r0) * 2048 + kt + kofs, As + wv * 512);
    gld16(A + (size_t)(row0 + 64 + r0) * 2048 + kt + kofs, As + 2048 + wv * 512);
    gld16(Bw + (size_t)(col0 + r0) * 2048 + kt + kofs, Bs + wv * 512);
    gld16(Bw + (size_t)(col0 + 64 + r0) * 2048 + kt + kofs, Bs + 2048 + wv * 512);
    __syncthreads();
    bf16x8 af[4], bfr[4];
    #pragma unroll
    for (int m = 0; m < 4; ++m)
      af[m] = *(const bf16x8*)(As + (wr * 64 + m * 16 + lr) * 32 + lk);
    #pragma unroll
    for (int n = 0; n < 4; ++n)
      bfr[n] = *(const bf16x8*)(Bs + (wc * 64 + n * 16 + lr) * 32 + lk);
    #pragma unroll
    for (int m = 0; m < 4; ++m)
      #pragma unroll
      for (int n = 0; n < 4; ++n)
        acc[m][n] = __builtin_amdgcn_mfma_f32_16x16x32_bf16(af[m], bfr[n], acc[m][n], 0, 0, 0);
  }
  const int rowb = row0 + wr * 64 + ((ln >> 4) << 2);
  const int colb = col0 + wc * 64 + (ln & 15);
  #pragma unroll
  for (int m = 0; m < 4; ++m)
    #pragma unroll
    for (int n = 0; n < 4; ++n)
      #pragma unroll
      for (int qq = 0; qq < 4; ++qq)
        Co[(size_t)(rowb + m * 16 + qq) * 2048 + colb + n * 16] = acc[m][n][qq];
}

// ---------------- post-GEMM: LoRA-up, decay, v-mix, kk-norm -> packed ----------------
__global__ __launch_bounds__(256)
void post_gemm_k(const float* __restrict__ v_first, const float* __restrict__ lora8,
                 const float* __restrict__ w0, const float* __restrict__ w2,
                 const float* __restrict__ a0, const float* __restrict__ a2,
                 const float* __restrict__ v0, const float* __restrict__ v2,
                 const float* __restrict__ k_k, const float* __restrict__ k_a,
                 char* __restrict__ packed) {
  const int rr = blockIdx.x;
  const int bq = rr >> 12, tq = rr & (T_LEN - 1);
  const int tid = threadIdx.x, c0 = tid * 8;
  const int hq = tid >> 1, j0 = (tid & 1) * 8;
  char* pb = packed + (size_t)((bq * 128 + hq) * T_LEN + tq) * REC;
  // load 8 j-packets (64 B): word {2m+1} holds [k | r]
  u32x4 pk0 = *(const u32x4*)(pb + j0 * 8);
  u32x4 pk1 = *(const u32x4*)(pb + j0 * 8 + 16);
  u32x4 pk2 = *(const u32x4*)(pb + j0 * 8 + 32);
  u32x4 pk3 = *(const u32x4*)(pb + j0 * 8 + 48);
  u32x4 uv = *(const u32x4*)(pb + 192 + 2 * j0);
  float kraw[8], vraw[8];
  kraw[0] = bflo(pk0[1]); kraw[1] = bflo(pk0[3]);
  kraw[2] = bflo(pk1[1]); kraw[3] = bflo(pk1[3]);
  kraw[4] = bflo(pk2[1]); kraw[5] = bflo(pk2[3]);
  kraw[6] = bflo(pk3[1]); kraw[7] = bflo(pk3[3]);
  #pragma unroll
  for (int ii = 0; ii < 4; ++ii) {
    vraw[2 * ii] = bflo(uv[ii]); vraw[2 * ii + 1] = bfhi(uv[ii]);
  }
  float vf[8] __attribute__((aligned(16)));
  const float* vfp = v_first + (size_t)rr * C_DIM + c0;
  *(f32x4*)vf = *(const f32x4*)vfp;
  *(f32x4*)(vf + 4) = *(const f32x4*)(vfp + 4);
  const float* lo = lora8 + (size_t)rr * 32;
  float w8[8] __attribute__((aligned(16)));
  float a8[8] __attribute__((aligned(16)));
  float v8[8] __attribute__((aligned(16)));
  *(f32x4*)w8 = *(const f32x4*)lo;        *(f32x4*)(w8 + 4) = *(const f32x4*)(lo + 4);
  *(f32x4*)a8 = *(const f32x4*)(lo + 8);  *(f32x4*)(a8 + 4) = *(const f32x4*)(lo + 12);
  *(f32x4*)v8 = *(const f32x4*)(lo + 16); *(f32x4*)(v8 + 4) = *(const f32x4*)(lo + 20);
  // vectorized LoRA-up accumulation (tables read as f32x4, not lane-strided scalars)
  float wr8[8] __attribute__((aligned(16)));
  float ar8[8] __attribute__((aligned(16)));
  float vr8[8] __attribute__((aligned(16)));
  *(f32x4*)wr8 = *(const f32x4*)(w0 + c0); *(f32x4*)(wr8 + 4) = *(const f32x4*)(w0 + c0 + 4);
  *(f32x4*)ar8 = *(const f32x4*)(a0 + c0); *(f32x4*)(ar8 + 4) = *(const f32x4*)(a0 + c0 + 4);
  *(f32x4*)vr8 = *(const f32x4*)(v0 + c0); *(f32x4*)(vr8 + 4) = *(const f32x4*)(v0 + c0 + 4);
  #pragma unroll
  for (int l = 0; l < 8; ++l) {
    float tw[8] __attribute__((aligned(16)));
    float ta[8] __attribute__((aligned(16)));
    float tv[8] __attribute__((aligned(16)));
    *(f32x4*)tw = *(const f32x4*)(w2 + (size_t)l * C_DIM + c0);
    *(f32x4*)(tw + 4) = *(const f32x4*)(w2 + (size_t)l * C_DIM + c0 + 4);
    *(f32x4*)ta = *(const f32x4*)(a2 + (size_t)l * C_DIM + c0);
    *(f32x4*)(ta + 4) = *(const f32x4*)(a2 + (size_t)l * C_DIM + c0 + 4);
    *(f32x4*)tv = *(const f32x4*)(v2 + (size_t)l * C_DIM + c0);
    *(f32x4*)(tv + 4) = *(const f32x4*)(v2 + (size_t)l * C_DIM + c0 + 4);
    #pragma unroll
    for (int ii = 0; ii < 8; ++ii) {
      wr8[ii] = fmaf(w8[l], tw[ii], wr8[ii]);
      ar8[ii] = fmaf(a8[l], ta[ii], ar8[ii]);
      vr8[ii] = fmaf(v8[l], tv[ii], vr8[ii]);
    }
  }
  float kk8[8] __attribute__((aligned(16)));
  float ka8[8] __attribute__((aligned(16)));
  *(f32x4*)kk8 = *(const f32x4*)(k_k + c0); *(f32x4*)(kk8 + 4) = *(const f32x4*)(k_k + c0 + 4);
  *(f32x4*)ka8 = *(const f32x4*)(k_a + c0); *(f32x4*)(ka8 + 4) = *(const f32x4*)(k_a + c0 + 4);
  float kk[8], av[8];
  float dec[8] __attribute__((aligned(16)));
  u16 wk[8];
  u16x8 wv2;
  float ss = 0.f;
  #pragma unroll
  for (int ii = 0; ii < 8; ++ii) {
    float w_ = -log1pf(expf(-wr8[ii])) - 0.5f;
    dec[ii] = expf(-expf(w_));
    float a_ = 1.f / (1.f + expf(-ar8[ii]));
    float vm = 1.f / (1.f + expf(-vr8[ii]));
    wv2[ii] = f2bf(fmaf(vf[ii] - vraw[ii], vm, vraw[ii]));
    kk[ii] = kraw[ii] * kk8[ii];
    ss = fmaf(kk[ii], kk[ii], ss);
    av[ii] = a_;
    wk[ii] = f2bf(kraw[ii] * fmaf(a_ - 1.f, ka8[ii], 1.f));
  }
  ss += __shfl_xor(ss, 1);
  ss += __shfl_xor(ss, 2);
  ss += __shfl_xor(ss, 4);
  float sc = 1.f / fmaxf(sqrtf(ss), 1e-8f);
  u16 wa[8], wb[8];
  #pragma unroll
  for (int ii = 0; ii < 8; ++ii) {
    float kn = kk[ii] * sc;
    wa[ii] = f2bf(-kn);
    wb[ii] = f2bf(kn * av[ii]);
  }
  // rebuild packets: word0 = a|b<<16, word1 = k | (old r hi16)
  u32x4 o0, o1, o2, o3;
  o0[0] = (u32)wa[0] | ((u32)wb[0] << 16); o0[1] = (u32)wk[0] | (pk0[1] & 0xffff0000u);
  o0[2] = (u32)wa[1] | ((u32)wb[1] << 16); o0[3] = (u32)wk[1] | (pk0[3] & 0xffff0000u);
  o1[0] = (u32)wa[2] | ((u32)wb[2] << 16); o1[1] = (u32)wk[2] | (pk1[1] & 0xffff0000u);
  o1[2] = (u32)wa[3] | ((u32)wb[3] << 16); o1[3] = (u32)wk[3] | (pk1[3] & 0xffff0000u);
  o2[0] = (u32)wa[4] | ((u32)wb[4] << 16); o2[1] = (u32)wk[4] | (pk2[1] & 0xffff0000u);
  o2[2] = (u32)wa[5] | ((u32)wb[5] << 16); o2[3] = (u32)wk[5] | (pk2[3] & 0xffff0000u);
  o3[0] = (u32)wa[6] | ((u32)wb[6] << 16); o3[1] = (u32)wk[6] | (pk3[1] & 0xffff0000u);
  o3[2] = (u32)wa[7] | ((u32)wb[7] << 16); o3[3] = (u32)wk[7] | (pk3[3] & 0xffff0000u);
  *(u32x4*)(pb + j0 * 8) = o0;
  *(u32x4*)(pb + j0 * 8 + 16) = o1;
  *(u32x4*)(pb + j0 * 8 + 32) = o2;
  *(u32x4*)(pb + j0 * 8 + 48) = o3;
  *(u16x8*)(pb + 192 + 2 * j0) = wv2;
  *(f32x4*)(pb + 128 + 4 * j0) = *(f32x4*)dec;
  *(f32x4*)(pb + 128 + 4 * j0 + 16) = *(f32x4*)(dec + 4);
}

// ---------------- sequential RWKV7 scan: 1 head / 4-wave block, 1 elem/lane ----------------
// (r7 proven config: 2-deep register pipeline over the LDS chunk)
__device__ __forceinline__ void stage(const char* g, char* l, int wv, int ln) {
  gld16(g + wv * 1024 + ln * 16, l + wv * 1024);
  gld16(g + 4096 + wv * 1024 + ln * 16, l + 4096 + wv * 1024);
  gld16(g + 8192 + wv * 1024 + ln * 16, l + 8192 + wv * 1024);
  if (wv < 2) gld16(g + 12288 + wv * 1024 + ln * 16, l + 12288 + wv * 1024);
}

__global__ __launch_bounds__(256)
void scan_k(char* __restrict__ packed) {
  // 2 chunk halves + 1 KB pad so tail prefetch over-reads stay in-bounds
  __shared__ __attribute__((aligned(16))) char bufm[2 * CHB + 1024];
  const int hb = blockIdx.x;
  const int tid = threadIdx.x;
  const int wv = tid >> 6, ln = tid & 63;
  const int j = ln & 15;
  const int i = wv * 4 + (ln >> 4);
  char* src = packed + (size_t)hb * (T_LEN * REC);
  float S = 0.f;
  stage(src, bufm, wv, ln);
  const int NC = T_LEN / CH;
  for (int c = 0; c < NC; ++c) {
    asm volatile("s_waitcnt vmcnt(0)" ::: "memory");
    __syncthreads();
    if (c + 1 < NC)
      stage(src + (size_t)(c + 1) * CHB, bufm + ((c + 1) & 1) * CHB, wv, ln);
    const char* Bp = bufm + (c & 1) * CHB;
    float* yg = (float*)(src + (size_t)c * CHB);
    const char* p0 = Bp + j * 8;         // [a|b][k|r] packet, +t*REC
    const char* pd = Bp + 128 + j * 4;   // dec f32
    const char* pv = Bp + 192 + i * 2;   // v bf16
    // preload steps 0,1
    u32x2 kA = *(const u32x2*)(p0);
    float dA = *(const float*)(pd);
    u32 vA = *(const u16*)(pv);
    u32x2 kB = *(const u32x2*)(p0 + REC);
    float dB = *(const float*)(pd + REC);
    u32 vB = *(const u16*)(pv + REC);
    for (int t = 0; t < CH; t += 2) {
      // prefetch t+2 (over-reads land in pad, discarded at chunk restart)
      u32x2 nkA = *(const u32x2*)(p0 + (t + 2) * REC);
      float ndA = *(const float*)(pd + (t + 2) * REC);
      u32 nvA = *(const u16*)(pv + (t + 2) * REC);
      {
        float a_ = bflo(kA[0]), b_ = bfhi(kA[0]);
        float k_ = bflo(kA[1]), r_ = bfhi(kA[1]);
        float v_ = bflo(vA);
        float sa = red16(S * a_);
        S = fmaf(S, dA, fmaf(sa, b_, v_ * k_));
        float yv = red16(S * r_);
        if (j == 0) yg[t * (REC / 4) + 32 + i] = yv;
      }
      kA = nkA; dA = ndA; vA = nvA;
      // prefetch t+3
      u32x2 nkB = *(const u32x2*)(p0 + (t + 3) * REC);
      float ndB = *(const float*)(pd + (t + 3) * REC);
      u32 nvB = *(const u16*)(pv + (t + 3) * REC);
      {
        float a_ = bflo(kB[0]), b_ = bfhi(kB[0]);
        float k_ = bflo(kB[1]), r_ = bfhi(kB[1]);
        float v_ = bflo(vB);
        float sa = red16(S * a_);
        S = fmaf(S, dB, fmaf(sa, b_, v_ * k_));
        float yv = red16(S * r_);
        if (j == 0) yg[(t + 1) * (REC / 4) + 32 + i] = yv;
      }
      kB = nkB; dB = ndB; vB = nvB;
    }
  }
}

// ---------------- GroupNorm + residual + gate -> bf16 ----------------
__global__ __launch_bounds__(256)
void post_gn_k(const char* __restrict__ packed, const float* __restrict__ lora8,
               const float* __restrict__ g2, const float* __restrict__ ln_g,
               const float* __restrict__ ln_b, const float* __restrict__ r_k,
               u16* __restrict__ og) {
  const int rr = blockIdx.x;
  const int bq = rr >> 12, tq = rr & (T_LEN - 1);
  const int tid = threadIdx.x, c0 = tid * 8;
  const int hq = tid >> 1, j0 = (tid & 1) * 8;
  const char* pb = packed + (size_t)((bq * 128 + hq) * T_LEN + tq) * REC;
  float rv[8], kv[8], vv[8];
  u32x4 pk0 = *(const u32x4*)(pb + j0 * 8);
  u32x4 pk1 = *(const u32x4*)(pb + j0 * 8 + 16);
  u32x4 pk2 = *(const u32x4*)(pb + j0 * 8 + 32);
  u32x4 pk3 = *(const u32x4*)(pb + j0 * 8 + 48);
  kv[0] = bflo(pk0[1]); rv[0] = bfhi(pk0[1]); kv[1] = bflo(pk0[3]); rv[1] = bfhi(pk0[3]);
  kv[2] = bflo(pk1[1]); rv[2] = bfhi(pk1[1]); kv[3] = bflo(pk1[3]); rv[3] = bfhi(pk1[3]);
  kv[4] = bflo(pk2[1]); rv[4] = bfhi(pk2[1]); kv[5] = bflo(pk2[3]); rv[5] = bfhi(pk2[3]);
  kv[6] = bflo(pk3[1]); rv[6] = bfhi(pk3[1]); kv[7] = bflo(pk3[3]); rv[7] = bfhi(pk3[3]);
  u32x4 uv = *(const u32x4*)(pb + 192 + 2 * j0);
  #pragma unroll
  for (int ii = 0; ii < 4; ++ii) {
    vv[2 * ii] = bflo(uv[ii]); vv[2 * ii + 1] = bfhi(uv[ii]);
  }
  f32x4 y0 = *(const f32x4*)(pb + 128 + 4 * j0);
  f32x4 y1 = *(const f32x4*)(pb + 128 + 4 * j0 + 16);
  float o[8];
  o[0] = y0[0]; o[1] = y0[1]; o[2] = y0[2]; o[3] = y0[3];
  o[4] = y1[0]; o[5] = y1[1]; o[6] = y1[2]; o[7] = y1[3];
  float g8[8] __attribute__((aligned(16)));
  const float* lo = lora8 + (size_t)rr * 32 + 24;
  *(f32x4*)g8 = *(const f32x4*)lo;
  *(f32x4*)(g8 + 4) = *(const f32x4*)(lo + 4);
  // vectorized gate projection accumulation
  float gg8[8] __attribute__((aligned(16)));
  #pragma unroll
  for (int ii = 0; ii < 8; ++ii) gg8[ii] = 0.f;
  #pragma unroll
  for (int l = 0; l < 8; ++l) {
    float tg[8] __attribute__((aligned(16)));
    *(f32x4*)tg = *(const f32x4*)(g2 + (size_t)l * C_DIM + c0);
    *(f32x4*)(tg + 4) = *(const f32x4*)(g2 + (size_t)l * C_DIM + c0 + 4);
    #pragma unroll
    for (int ii = 0; ii < 8; ++ii) gg8[ii] = fmaf(g8[l], tg[ii], gg8[ii]);
  }
  float rk8[8] __attribute__((aligned(16)));
  float lg8[8] __attribute__((aligned(16)));
  float lb8[8] __attribute__((aligned(16)));
  *(f32x4*)rk8 = *(const f32x4*)(r_k + c0); *(f32x4*)(rk8 + 4) = *(const f32x4*)(r_k + c0 + 4);
  *(f32x4*)lg8 = *(const f32x4*)(ln_g + c0); *(f32x4*)(lg8 + 4) = *(const f32x4*)(ln_g + c0 + 4);
  *(f32x4*)lb8 = *(const f32x4*)(ln_b + c0); *(f32x4*)(lb8 + 4) = *(const f32x4*)(ln_b + c0 + 4);
  float s1 = 0.f, s2 = 0.f, srk = 0.f;
  #pragma unroll
  for (int ii = 0; ii < 8; ++ii) {
    s1 += o[ii];
    s2 = fmaf(o[ii], o[ii], s2);
    srk = fmaf(rv[ii] * kv[ii], rk8[ii], srk);
  }
  s1 += __shfl_xor(s1, 1); s1 += __shfl_xor(s1, 2); s1 += __shfl_xor(s1, 4);
  s2 += __shfl_xor(s2, 1); s2 += __shfl_xor(s2, 2); s2 += __shfl_xor(s2, 4);
  srk += __shfl_xor(srk, 1); srk += __shfl_xor(srk, 2); srk += __shfl_xor(srk, 4);
  float mu = s1 * (1.f / 64.f);
  float var = s2 * (1.f / 64.f) - mu * mu;
  float rstd = rsqrtf(var + 0.00064f);
  u16x8 ov;
  #pragma unroll
  for (int ii = 0; ii < 8; ++ii) {
    float on = fmaf((o[ii] - mu) * rstd, lg8[ii], lb8[ii]);
    float o2 = fmaf(srk, vv[ii], on);
    ov[ii] = f2bf(o2 * gg8[ii]);
  }
  *(u16x8*)(og + (size_t)rr * C_DIM + c0) = ov;
}

extern "C" void kernel_launch(void* const* d_in, const int* in_sizes, int n_in,
                              void* d_out, int out_size, void* d_ws, size_t ws_size,
                              hipStream_t stream) {
  (void)in_sizes; (void)n_in; (void)out_size;
  const float* x      = (const float*)d_in[0];
  const float* v_first= (const float*)d_in[1];
  const float* x_r    = (const float*)d_in[2];
  const float* x_w    = (const float*)d_in[3];
  const float* x_k    = (const float*)d_in[4];
  const float* x_v    = (const float*)d_in[5];
  const float* x_a    = (const float*)d_in[6];
  const float* x_g    = (const float*)d_in[7];
  const float* w0     = (const float*)d_in[8];
  const float* w1     = (const float*)d_in[9];
  const float* w2     = (const float*)d_in[10];
  const float* a0     = (const float*)d_in[11];
  const float* a1     = (const float*)d_in[12];
  const float* a2     = (const float*)d_in[13];
  const float* v0     = (const float*)d_in[14];
  const float* v1     = (const float*)d_in[15];
  const float* v2     = (const float*)d_in[16];
  const float* g1     = (const float*)d_in[17];
  const float* g2     = (const float*)d_in[18];
  const float* k_k    = (const float*)d_in[19];
  const float* k_a    = (const float*)d_in[20];
  const float* r_k    = (const float*)d_in[21];
  const float* Wr     = (const float*)d_in[22];
  const float* Wk     = (const float*)d_in[23];
  const float* Wv     = (const float*)d_in[24];
  const float* Wo     = (const float*)d_in[25];
  const float* ln_g   = (const float*)d_in[26];
  const float* ln_b   = (const float*)d_in[27];

  if (ws_size < 370147328ull) return;
  char* ws = (char*)d_ws;
  u16* Wr_bf = (u16*)(ws + 0);            //  8 MB each, contiguous (conv indexes)
  u16* Wo_bf = Wr_bf + 3 * 4194304;
  u16* xr_bf = (u16*)(ws + 33554432);     // 32 MB each
  u16* xk_bf = xr_bf + 16777216;
  u16* xv_bf = xk_bf + 16777216;
  float* lora8 = (float*)(ws + 134217728); // 1 MB
  char* packed = ws + 135266304;           // 224 MB
  float* wt = (float*)packed;              // transposed LoRA tables (256 KB),
                                           // consumed before gemms overwrite
  u16* og = xr_bf;                         // reuse (dead after r-GEMM)
  float* out = (float*)d_out;

  conv_bf16_k<<<dim3(2048, 4), 256, 0, stream>>>(Wr, Wk, Wv, Wo, Wr_bf);
  trans_lora_k<<<dim3(8, 4), 256, 0, stream>>>(w1, a1, v1, g1, wt);

  mix_lora_k<<<8192, 256, 0, stream>>>(x, x_r, x_w, x_k, x_v, x_a, x_g,
                                       wt, xr_bf, xk_bf, xv_bf, lora8);

  gemm3_k<<<dim3(16, 64, 3), 256, 0, stream>>>(xk_bf, xr_bf, xv_bf,
                                               Wr_bf, packed);

  post_gemm_k<<<8192, 256, 0, stream>>>(v_first, lora8, w0, w2, a0, a2, v0, v2,
                                        k_k, k_a, packed);

  scan_k<<<256, 256, 0, stream>>>(packed);

  post_gn_k<<<8192, 256, 0, stream>>>(packed, lora8, g2, ln_g, ln_b, r_k, og);

  gemm_k<<<dim3(16, 64), 256, 0, stream>>>(og, Wo_bf, out);

  hipMemcpyAsync(out + 16777216, v_first, (size_t)16777216 * 4,
                 hipMemcpyDeviceToDevice, stream);
}

// Round 10
// 1373.352 us; speedup vs baseline: 1.2177x; 1.0552x over previous
//
#include <hip/hip_runtime.h>

#define T_LEN 4096
#define C_DIM 2048
#define REC 224          // packed record: 16x[a,b,k,r] bf16 128B | dec/y f32 64B | v bf16 32B
#define CH 64            // scan steps per LDS chunk (64*224 = 14336 B)
#define CHB (CH * REC)

typedef __attribute__((ext_vector_type(4))) float f32x4;
typedef __attribute__((ext_vector_type(8))) __bf16 bf16x8;
typedef __attribute__((ext_vector_type(8))) unsigned short u16x8;
typedef __attribute__((ext_vector_type(4))) unsigned int u32x4;
typedef __attribute__((ext_vector_type(2))) unsigned int u32x2;
typedef unsigned short u16;
typedef unsigned int u32;

typedef __attribute__((address_space(1))) const void* as1cv;
typedef __attribute__((address_space(3))) void* as3v;

__device__ __forceinline__ void gld16(const void* g, void* l) {
  __builtin_amdgcn_global_load_lds((as1cv)g, (as3v)l, 16, 0, 0);
}

__device__ __forceinline__ u16 f2bf(float f) {
  union { float f; unsigned u; } x; x.f = f;
  return (u16)((x.u + 0x7fffu + ((x.u >> 16) & 1u)) >> 16);
}
__device__ __forceinline__ float bflo(unsigned u) {
  union { unsigned u; float f; } x; x.u = u << 16; return x.f;
}
__device__ __forceinline__ float bfhi(unsigned u) {
  union { unsigned u; float f; } x; x.u = u & 0xffff0000u; return x.f;
}
// sum over a 16-lane row via DPP (xor1, xor2, row_ror:4, row_ror:8) — all lanes get the sum
__device__ __forceinline__ float red16(float x) {
  int a;
  a = __builtin_amdgcn_update_dpp(0, __builtin_bit_cast(int, x), 0xB1, 0xF, 0xF, true);
  x += __builtin_bit_cast(float, a);
  a = __builtin_amdgcn_update_dpp(0, __builtin_bit_cast(int, x), 0x4E, 0xF, 0xF, true);
  x += __builtin_bit_cast(float, a);
  a = __builtin_amdgcn_update_dpp(0, __builtin_bit_cast(int, x), 0x124, 0xF, 0xF, true);
  x += __builtin_bit_cast(float, a);
  a = __builtin_amdgcn_update_dpp(0, __builtin_bit_cast(int, x), 0x128, 0xF, 0xF, true);
  x += __builtin_bit_cast(float, a);
  return x;
}
__device__ __forceinline__ f32x4 red16v(f32x4 v) {
  v[0] = red16(v[0]); v[1] = red16(v[1]);
  v[2] = red16(v[2]); v[3] = red16(v[3]);
  return v;
}

// ---------------- weights fp32 -> bf16 (all four in one launch) ----------------
__global__ __launch_bounds__(256)
void conv_bf16_k(const float* __restrict__ s0, const float* __restrict__ s1,
                 const float* __restrict__ s2, const float* __restrict__ s3,
                 u16* __restrict__ d0) {
  const float* s = (blockIdx.y == 0) ? s0 : (blockIdx.y == 1) ? s1
                   : (blockIdx.y == 2) ? s2 : s3;
  u16* d = d0 + (size_t)blockIdx.y * 4194304;
  int i = (blockIdx.x * 256 + threadIdx.x) * 8;
  f32x4 a = *(const f32x4*)(s + i);
  f32x4 b = *(const f32x4*)(s + i + 4);
  u16x8 o;
  o[0] = f2bf(a[0]); o[1] = f2bf(a[1]); o[2] = f2bf(a[2]); o[3] = f2bf(a[3]);
  o[4] = f2bf(b[0]); o[5] = f2bf(b[1]); o[6] = f2bf(b[2]); o[7] = f2bf(b[3]);
  *(u16x8*)(d + i) = o;
}

// ---------------- LoRA-down matrices: (C x 8) -> (8 x C) fp32 transpose ----------------
__global__ __launch_bounds__(256)
void trans_lora_k(const float* __restrict__ w1, const float* __restrict__ a1,
                  const float* __restrict__ v1, const float* __restrict__ g1,
                  float* __restrict__ wt) {
  const float* s = (blockIdx.y == 0) ? w1 : (blockIdx.y == 1) ? a1
                   : (blockIdx.y == 2) ? v1 : g1;
  float* d = wt + (size_t)blockIdx.y * (8 * C_DIM);
  int c = blockIdx.x * 256 + threadIdx.x;    // grid.x = 8
  f32x4 lo = *(const f32x4*)(s + c * 8);
  f32x4 hi = *(const f32x4*)(s + c * 8 + 4);
  d[0 * C_DIM + c] = lo[0]; d[1 * C_DIM + c] = lo[1];
  d[2 * C_DIM + c] = lo[2]; d[3 * C_DIM + c] = lo[3];
  d[4 * C_DIM + c] = hi[0]; d[5 * C_DIM + c] = hi[1];
  d[6 * C_DIM + c] = hi[2]; d[7 * C_DIM + c] = hi[3];
}

// ---------------- mix + LoRA down (strided mapping, all loads coalesced) ----------------
__global__ __launch_bounds__(256)
void mix_lora_k(const float* __restrict__ x,
                const float* __restrict__ xrw, const float* __restrict__ xww,
                const float* __restrict__ xkw, const float* __restrict__ xvw,
                const float* __restrict__ xaw, const float* __restrict__ xgw,
                const float* __restrict__ wt,   // 4 transposed tables, 8xC each
                u16* __restrict__ xr_bf, u16* __restrict__ xk_bf,
                u16* __restrict__ xv_bf, float* __restrict__ lora8) {
  const int rr = blockIdx.x;
  const int t = rr & (T_LEN - 1);
  const int tid = threadIdx.x;
  const float* xrow = x + (size_t)rr * C_DIM;
  float wl[8], al[8], vl[8], gl[8];
  #pragma unroll
  for (int l = 0; l < 8; ++l) { wl[l] = 0.f; al[l] = 0.f; vl[l] = 0.f; gl[l] = 0.f; }
  #pragma unroll
  for (int ii = 0; ii < 8; ++ii) {
    const int c = ii * 256 + tid;
    float xi = xrow[c];
    float xpv = t ? xrow[c - C_DIM] : 0.f;
    float dx = xpv - xi;
    float xr_ = fmaf(dx, xrw[c], xi);
    float xw_ = fmaf(dx, xww[c], xi);
    float xk_ = fmaf(dx, xkw[c], xi);
    float xv_ = fmaf(dx, xvw[c], xi);
    float xa_ = fmaf(dx, xaw[c], xi);
    float xg_ = fmaf(dx, xgw[c], xi);
    xr_bf[(size_t)rr * C_DIM + c] = f2bf(xr_);
    xk_bf[(size_t)rr * C_DIM + c] = f2bf(xk_);
    xv_bf[(size_t)rr * C_DIM + c] = f2bf(xv_);
    #pragma unroll
    for (int l = 0; l < 8; ++l) {
      wl[l] = fmaf(xw_, wt[l * C_DIM + c], wl[l]);
      al[l] = fmaf(xa_, wt[16384 + l * C_DIM + c], al[l]);
      vl[l] = fmaf(xv_, wt[32768 + l * C_DIM + c], vl[l]);
      gl[l] = fmaf(xg_, wt[49152 + l * C_DIM + c], gl[l]);
    }
  }
  // row-reduce (16 lanes) all 32 partials via DPP — pure VALU
  f32x4 w03 = red16v((f32x4){wl[0], wl[1], wl[2], wl[3]});
  f32x4 w47 = red16v((f32x4){wl[4], wl[5], wl[6], wl[7]});
  f32x4 a03 = red16v((f32x4){al[0], al[1], al[2], al[3]});
  f32x4 a47 = red16v((f32x4){al[4], al[5], al[6], al[7]});
  f32x4 v03 = red16v((f32x4){vl[0], vl[1], vl[2], vl[3]});
  f32x4 v47 = red16v((f32x4){vl[4], vl[5], vl[6], vl[7]});
  f32x4 g03 = red16v((f32x4){gl[0], gl[1], gl[2], gl[3]});
  f32x4 g47 = red16v((f32x4){gl[4], gl[5], gl[6], gl[7]});
  __shared__ __attribute__((aligned(16))) float red2[16][32];
  const int row = tid >> 4;          // 16 rows of 16 lanes
  if ((tid & 15) == 0) {
    *(f32x4*)&red2[row][0] = w03;  *(f32x4*)&red2[row][4] = w47;
    *(f32x4*)&red2[row][8] = a03;  *(f32x4*)&red2[row][12] = a47;
    *(f32x4*)&red2[row][16] = v03; *(f32x4*)&red2[row][20] = v47;
    *(f32x4*)&red2[row][24] = g03; *(f32x4*)&red2[row][28] = g47;
  }
  __syncthreads();
  if (tid < 32) {
    float s = 0.f;
    #pragma unroll
    for (int r = 0; r < 16; ++r) s += red2[r][tid];
    int mat = tid >> 3;
    if (mat == 0) s = tanhf(s);
    else if (mat == 3) s = 1.f / (1.f + expf(-s));
    lora8[(size_t)rr * 32 + tid] = s;
  }
}

// ---------------- 256x256 8-wave double-buffered MFMA GEMM (counted vmcnt) ----------------
// C[m,n] = sum_k A[m,k]*Bw[n,k].  BK=64 split into two K-halves; per K-tile:
// 4 phases {kh x mh}, staging one (kt+1,kh) unit per kh-pair, vmcnt(4) at kh
// boundaries so the just-issued unit stays in flight (never vmcnt(0) in loop).
// LDS swizzle: slot ^= (row>>1)&3 applied to BOTH staging source and ds_read.
__device__ __forceinline__ int swzslot(int row, int slot) {
  return slot ^ ((row >> 1) & 3);
}

__global__ __launch_bounds__(512)
void gemm8_k(const u16* __restrict__ A0, const u16* __restrict__ A1,
             const u16* __restrict__ A2, const u16* __restrict__ B0,
             const u16* __restrict__ B1, const u16* __restrict__ B2,
             char* __restrict__ out, int pmode) {
  extern __shared__ __attribute__((aligned(16))) char smem[];
  u16* Asm = (u16*)smem;               // [db][kh][8192] u16  (64 KB)
  u16* Bsm = (u16*)(smem + 65536);     // [db][kh][8192] u16  (64 KB)
  const int z = blockIdx.z;
  const u16* A = (z == 0) ? A0 : (z == 1) ? A1 : A2;
  const u16* Bw = (z == 0) ? B0 : (z == 1) ? B1 : B2;
  const int sbase = (z == 0) ? 4 : (z == 1) ? 6 : 192;
  const int sstr = (z == 2) ? 2 : 8;
  const int tid = threadIdx.x;
  const int wv = tid >> 6, ln = tid & 63;
  const int wr = wv >> 2, wc = wv & 3;         // 2 x 4 wave grid
  const int row0 = blockIdx.y * 256, col0 = blockIdx.x * 256;
  // staging geometry: thread covers 16B at (row = tid>>2, phys slot = tid&3)
  const int s_rw = tid >> 2;
  const int s_slotL = (tid & 3) ^ ((s_rw >> 1) & 3);   // logical slot fetched
  // loop-invariant fragment offsets (u16 elements within a [256][32] block)
  int aoff[8], boff[4];
  #pragma unroll
  for (int m = 0; m < 8; ++m) {
    int row = wr * 128 + m * 16 + (ln & 15);
    aoff[m] = row * 32 + swzslot(row, ln >> 4) * 8;
  }
  #pragma unroll
  for (int n = 0; n < 4; ++n) {
    int row = wc * 64 + n * 16 + (ln & 15);
    boff[n] = row * 32 + swzslot(row, ln >> 4) * 8;
  }
  f32x4 acc[8][4];
  #pragma unroll
  for (int m = 0; m < 8; ++m)
    #pragma unroll
    for (int n = 0; n < 4; ++n) acc[m][n] = (f32x4){0.f, 0.f, 0.f, 0.f};

  auto abase = [&](int db, int kh) -> u16* { return Asm + (db * 2 + kh) * 8192; };
  auto bbase = [&](int db, int kh) -> u16* { return Bsm + (db * 2 + kh) * 8192; };
  auto stage1 = [&](const u16* src, int baserow, u16* lbase, int kh, int skt, int rblk) {
    const u16* g = src + (size_t)(baserow + rblk * 128 + s_rw) * 2048
                   + skt * 64 + kh * 32 + s_slotL * 8;
    gld16(g, lbase + rblk * 4096 + wv * 512);
  };
  auto khblock = [&](int db, int kh, int skt, bool doStage) {
    const u16* Ab = abase(db, kh);
    const u16* Bb = bbase(db, kh);
    const int sdb = db ^ 1;
    bf16x8 bf[4], af[4];
    #pragma unroll
    for (int n = 0; n < 4; ++n) bf[n] = *(const bf16x8*)(Bb + boff[n]);
    #pragma unroll
    for (int m = 0; m < 4; ++m) af[m] = *(const bf16x8*)(Ab + aoff[m]);
    if (doStage) {
      stage1(A, row0, abase(sdb, kh), kh, skt, 0);
      stage1(A, row0, abase(sdb, kh), kh, skt, 1);
    }
    __builtin_amdgcn_s_setprio(1);
    #pragma unroll
    for (int m = 0; m < 4; ++m)
      #pragma unroll
      for (int n = 0; n < 4; ++n)
        acc[m][n] = __builtin_amdgcn_mfma_f32_16x16x32_bf16(af[m], bf[n], acc[m][n], 0, 0, 0);
    __builtin_amdgcn_s_setprio(0);
    #pragma unroll
    for (int m = 0; m < 4; ++m) af[m] = *(const bf16x8*)(Ab + aoff[4 + m]);
    if (doStage) {
      stage1(Bw, col0, bbase(sdb, kh), kh, skt, 0);
      stage1(Bw, col0, bbase(sdb, kh), kh, skt, 1);
    }
    __builtin_amdgcn_s_setprio(1);
    #pragma unroll
    for (int m = 0; m < 4; ++m)
      #pragma unroll
      for (int n = 0; n < 4; ++n)
        acc[4 + m][n] = __builtin_amdgcn_mfma_f32_16x16x32_bf16(af[m], bf[n], acc[4 + m][n], 0, 0, 0);
    __builtin_amdgcn_s_setprio(0);
  };

  // prologue: stage S(0,0), S(0,1)
  stage1(A, row0, abase(0, 0), 0, 0, 0); stage1(A, row0, abase(0, 0), 0, 0, 1);
  stage1(Bw, col0, bbase(0, 0), 0, 0, 0); stage1(Bw, col0, bbase(0, 0), 0, 0, 1);
  stage1(A, row0, abase(0, 1), 1, 0, 0); stage1(A, row0, abase(0, 1), 1, 0, 1);
  stage1(Bw, col0, bbase(0, 1), 1, 0, 0); stage1(Bw, col0, bbase(0, 1), 1, 0, 1);
  asm volatile("s_waitcnt vmcnt(4)" ::: "memory");
  __builtin_amdgcn_s_barrier();
  for (int kt = 0; kt < 31; ++kt) {
    const int db = kt & 1;
    khblock(db, 0, kt + 1, true);
    asm volatile("s_waitcnt vmcnt(4)" ::: "memory");
    __builtin_amdgcn_s_barrier();
    khblock(db, 1, kt + 1, true);
    asm volatile("s_waitcnt vmcnt(4)" ::: "memory");
    __builtin_amdgcn_s_barrier();
  }
  khblock(1, 0, 0, false);
  asm volatile("s_waitcnt vmcnt(0)" ::: "memory");
  __builtin_amdgcn_s_barrier();
  khblock(1, 1, 0, false);

  const int rowb = row0 + wr * 128 + ((ln >> 4) << 2);
  const int colb = col0 + wc * 64 + (ln & 15);
  #pragma unroll
  for (int m = 0; m < 8; ++m)
    #pragma unroll
    for (int n = 0; n < 4; ++n)
      #pragma unroll
      for (int qq = 0; qq < 4; ++qq) {
        int row = rowb + m * 16 + qq;
        int col = colb + n * 16;
        float val = acc[m][n][qq];
        if (pmode == 0) {
          ((float*)out)[(size_t)row * 2048 + col] = val;
        } else {
          int bq = row >> 12, tq = row & (T_LEN - 1);
          int hq = col >> 4, jq = col & 15;
          *(u16*)(out + (size_t)((bq * 128 + hq) * T_LEN + tq) * REC
                  + sbase + jq * sstr) = f2bf(val);
        }
      }
}

// ---------------- post-GEMM: LoRA-up, decay, v-mix, kk-norm -> packed ----------------
__global__ __launch_bounds__(256)
void post_gemm_k(const float* __restrict__ v_first, const float* __restrict__ lora8,
                 const float* __restrict__ w0, const float* __restrict__ w2,
                 const float* __restrict__ a0, const float* __restrict__ a2,
                 const float* __restrict__ v0, const float* __restrict__ v2,
                 const float* __restrict__ k_k, const float* __restrict__ k_a,
                 char* __restrict__ packed) {
  const int rr = blockIdx.x;
  const int bq = rr >> 12, tq = rr & (T_LEN - 1);
  const int tid = threadIdx.x, c0 = tid * 8;
  const int hq = tid >> 1, j0 = (tid & 1) * 8;
  char* pb = packed + (size_t)((bq * 128 + hq) * T_LEN + tq) * REC;
  // load 8 j-packets (64 B): word {2m+1} holds [k | r]
  u32x4 pk0 = *(const u32x4*)(pb + j0 * 8);
  u32x4 pk1 = *(const u32x4*)(pb + j0 * 8 + 16);
  u32x4 pk2 = *(const u32x4*)(pb + j0 * 8 + 32);
  u32x4 pk3 = *(const u32x4*)(pb + j0 * 8 + 48);
  u32x4 uv = *(const u32x4*)(pb + 192 + 2 * j0);
  float kraw[8], vraw[8];
  kraw[0] = bflo(pk0[1]); kraw[1] = bflo(pk0[3]);
  kraw[2] = bflo(pk1[1]); kraw[3] = bflo(pk1[3]);
  kraw[4] = bflo(pk2[1]); kraw[5] = bflo(pk2[3]);
  kraw[6] = bflo(pk3[1]); kraw[7] = bflo(pk3[3]);
  #pragma unroll
  for (int ii = 0; ii < 4; ++ii) {
    vraw[2 * ii] = bflo(uv[ii]); vraw[2 * ii + 1] = bfhi(uv[ii]);
  }
  float vf[8] __attribute__((aligned(16)));
  const float* vfp = v_first + (size_t)rr * C_DIM + c0;
  *(f32x4*)vf = *(const f32x4*)vfp;
  *(f32x4*)(vf + 4) = *(const f32x4*)(vfp + 4);
  const float* lo = lora8 + (size_t)rr * 32;
  float w8[8] __attribute__((aligned(16)));
  float a8[8] __attribute__((aligned(16)));
  float v8[8] __attribute__((aligned(16)));
  *(f32x4*)w8 = *(const f32x4*)lo;        *(f32x4*)(w8 + 4) = *(const f32x4*)(lo + 4);
  *(f32x4*)a8 = *(const f32x4*)(lo + 8);  *(f32x4*)(a8 + 4) = *(const f32x4*)(lo + 12);
  *(f32x4*)v8 = *(const f32x4*)(lo + 16); *(f32x4*)(v8 + 4) = *(const f32x4*)(lo + 20);
  // vectorized LoRA-up accumulation (tables read as f32x4, not lane-strided scalars)
  float wr8[8] __attribute__((aligned(16)));
  float ar8[8] __attribute__((aligned(16)));
  float vr8[8] __attribute__((aligned(16)));
  *(f32x4*)wr8 = *(const f32x4*)(w0 + c0); *(f32x4*)(wr8 + 4) = *(const f32x4*)(w0 + c0 + 4);
  *(f32x4*)ar8 = *(const f32x4*)(a0 + c0); *(f32x4*)(ar8 + 4) = *(const f32x4*)(a0 + c0 + 4);
  *(f32x4*)vr8 = *(const f32x4*)(v0 + c0); *(f32x4*)(vr8 + 4) = *(const f32x4*)(v0 + c0 + 4);
  #pragma unroll
  for (int l = 0; l < 8; ++l) {
    float tw[8] __attribute__((aligned(16)));
    float ta[8] __attribute__((aligned(16)));
    float tv[8] __attribute__((aligned(16)));
    *(f32x4*)tw = *(const f32x4*)(w2 + (size_t)l * C_DIM + c0);
    *(f32x4*)(tw + 4) = *(const f32x4*)(w2 + (size_t)l * C_DIM + c0 + 4);
    *(f32x4*)ta = *(const f32x4*)(a2 + (size_t)l * C_DIM + c0);
    *(f32x4*)(ta + 4) = *(const f32x4*)(a2 + (size_t)l * C_DIM + c0 + 4);
    *(f32x4*)tv = *(const f32x4*)(v2 + (size_t)l * C_DIM + c0);
    *(f32x4*)(tv + 4) = *(const f32x4*)(v2 + (size_t)l * C_DIM + c0 + 4);
    #pragma unroll
    for (int ii = 0; ii < 8; ++ii) {
      wr8[ii] = fmaf(w8[l], tw[ii], wr8[ii]);
      ar8[ii] = fmaf(a8[l], ta[ii], ar8[ii]);
      vr8[ii] = fmaf(v8[l], tv[ii], vr8[ii]);
    }
  }
  float kk8[8] __attribute__((aligned(16)));
  float ka8[8] __attribute__((aligned(16)));
  *(f32x4*)kk8 = *(const f32x4*)(k_k + c0); *(f32x4*)(kk8 + 4) = *(const f32x4*)(k_k + c0 + 4);
  *(f32x4*)ka8 = *(const f32x4*)(k_a + c0); *(f32x4*)(ka8 + 4) = *(const f32x4*)(k_a + c0 + 4);
  float kk[8], av[8];
  float dec[8] __attribute__((aligned(16)));
  u16 wk[8];
  u16x8 wv2;
  float ss = 0.f;
  #pragma unroll
  for (int ii = 0; ii < 8; ++ii) {
    float w_ = -log1pf(expf(-wr8[ii])) - 0.5f;
    dec[ii] = expf(-expf(w_));
    float a_ = 1.f / (1.f + expf(-ar8[ii]));
    float vm = 1.f / (1.f + expf(-vr8[ii]));
    wv2[ii] = f2bf(fmaf(vf[ii] - vraw[ii], vm, vraw[ii]));
    kk[ii] = kraw[ii] * kk8[ii];
    ss = fmaf(kk[ii], kk[ii], ss);
    av[ii] = a_;
    wk[ii] = f2bf(kraw[ii] * fmaf(a_ - 1.f, ka8[ii], 1.f));
  }
  ss += __shfl_xor(ss, 1);
  ss += __shfl_xor(ss, 2);
  ss += __shfl_xor(ss, 4);
  float sc = 1.f / fmaxf(sqrtf(ss), 1e-8f);
  u16 wa[8], wb[8];
  #pragma unroll
  for (int ii = 0; ii < 8; ++ii) {
    float kn = kk[ii] * sc;
    wa[ii] = f2bf(-kn);
    wb[ii] = f2bf(kn * av[ii]);
  }
  // rebuild packets: word0 = a|b<<16, word1 = k | (old r hi16)
  u32x4 o0, o1, o2, o3;
  o0[0] = (u32)wa[0] | ((u32)wb[0] << 16); o0[1] = (u32)wk[0] | (pk0[1] & 0xffff0000u);
  o0[2] = (u32)wa[1] | ((u32)wb[1] << 16); o0[3] = (u32)wk[1] | (pk0[3] & 0xffff0000u);
  o1[0] = (u32)wa[2] | ((u32)wb[2] << 16); o1[1] = (u32)wk[2] | (pk1[1] & 0xffff0000u);
  o1[2] = (u32)wa[3] | ((u32)wb[3] << 16); o1[3] = (u32)wk[3] | (pk1[3] & 0xffff0000u);
  o2[0] = (u32)wa[4] | ((u32)wb[4] << 16); o2[1] = (u32)wk[4] | (pk2[1] & 0xffff0000u);
  o2[2] = (u32)wa[5] | ((u32)wb[5] << 16); o2[3] = (u32)wk[5] | (pk2[3] & 0xffff0000u);
  o3[0] = (u32)wa[6] | ((u32)wb[6] << 16); o3[1] = (u32)wk[6] | (pk3[1] & 0xffff0000u);
  o3[2] = (u32)wa[7] | ((u32)wb[7] << 16); o3[3] = (u32)wk[7] | (pk3[3] & 0xffff0000u);
  *(u32x4*)(pb + j0 * 8) = o0;
  *(u32x4*)(pb + j0 * 8 + 16) = o1;
  *(u32x4*)(pb + j0 * 8 + 32) = o2;
  *(u32x4*)(pb + j0 * 8 + 48) = o3;
  *(u16x8*)(pb + 192 + 2 * j0) = wv2;
  *(f32x4*)(pb + 128 + 4 * j0) = *(f32x4*)dec;
  *(f32x4*)(pb + 128 + 4 * j0 + 16) = *(f32x4*)(dec + 4);
}

// ---------------- sequential RWKV7 scan: 1 head / 4-wave block, 1 elem/lane ----------------
// (r7 proven config: 2-deep register pipeline over the LDS chunk)
__device__ __forceinline__ void stage(const char* g, char* l, int wv, int ln) {
  gld16(g + wv * 1024 + ln * 16, l + wv * 1024);
  gld16(g + 4096 + wv * 1024 + ln * 16, l + 4096 + wv * 1024);
  gld16(g + 8192 + wv * 1024 + ln * 16, l + 8192 + wv * 1024);
  if (wv < 2) gld16(g + 12288 + wv * 1024 + ln * 16, l + 12288 + wv * 1024);
}

__global__ __launch_bounds__(256)
void scan_k(char* __restrict__ packed) {
  // 2 chunk halves + 1 KB pad so tail prefetch over-reads stay in-bounds
  __shared__ __attribute__((aligned(16))) char bufm[2 * CHB + 1024];
  const int hb = blockIdx.x;
  const int tid = threadIdx.x;
  const int wv = tid >> 6, ln = tid & 63;
  const int j = ln & 15;
  const int i = wv * 4 + (ln >> 4);
  char* src = packed + (size_t)hb * (T_LEN * REC);
  float S = 0.f;
  stage(src, bufm, wv, ln);
  const int NC = T_LEN / CH;
  for (int c = 0; c < NC; ++c) {
    asm volatile("s_waitcnt vmcnt(0)" ::: "memory");
    __syncthreads();
    if (c + 1 < NC)
      stage(src + (size_t)(c + 1) * CHB, bufm + ((c + 1) & 1) * CHB, wv, ln);
    const char* Bp = bufm + (c & 1) * CHB;
    float* yg = (float*)(src + (size_t)c * CHB);
    const char* p0 = Bp + j * 8;         // [a|b][k|r] packet, +t*REC
    const char* pd = Bp + 128 + j * 4;   // dec f32
    const char* pv = Bp + 192 + i * 2;   // v bf16
    // preload steps 0,1
    u32x2 kA = *(const u32x2*)(p0);
    float dA = *(const float*)(pd);
    u32 vA = *(const u16*)(pv);
    u32x2 kB = *(const u32x2*)(p0 + REC);
    float dB = *(const float*)(pd + REC);
    u32 vB = *(const u16*)(pv + REC);
    for (int t = 0; t < CH; t += 2) {
      // prefetch t+2 (over-reads land in pad, discarded at chunk restart)
      u32x2 nkA = *(const u32x2*)(p0 + (t + 2) * REC);
      float ndA = *(const float*)(pd + (t + 2) * REC);
      u32 nvA = *(const u16*)(pv + (t + 2) * REC);
      {
        float a_ = bflo(kA[0]), b_ = bfhi(kA[0]);
        float k_ = bflo(kA[1]), r_ = bfhi(kA[1]);
        float v_ = bflo(vA);
        float sa = red16(S * a_);
        S = fmaf(S, dA, fmaf(sa, b_, v_ * k_));
        float yv = red16(S * r_);
        if (j == 0) yg[t * (REC / 4) + 32 + i] = yv;
      }
      kA = nkA; dA = ndA; vA = nvA;
      // prefetch t+3
      u32x2 nkB = *(const u32x2*)(p0 + (t + 3) * REC);
      float ndB = *(const float*)(pd + (t + 3) * REC);
      u32 nvB = *(const u16*)(pv + (t + 3) * REC);
      {
        float a_ = bflo(kB[0]), b_ = bfhi(kB[0]);
        float k_ = bflo(kB[1]), r_ = bfhi(kB[1]);
        float v_ = bflo(vB);
        float sa = red16(S * a_);
        S = fmaf(S, dB, fmaf(sa, b_, v_ * k_));
        float yv = red16(S * r_);
        if (j == 0) yg[(t + 1) * (REC / 4) + 32 + i] = yv;
      }
      kB = nkB; dB = ndB; vB = nvB;
    }
  }
}

// ---------------- GroupNorm + residual + gate -> bf16 ----------------
__global__ __launch_bounds__(256)
void post_gn_k(const char* __restrict__ packed, const float* __restrict__ lora8,
               const float* __restrict__ g2, const float* __restrict__ ln_g,
               const float* __restrict__ ln_b, const float* __restrict__ r_k,
               u16* __restrict__ og) {
  const int rr = blockIdx.x;
  const int bq = rr >> 12, tq = rr & (T_LEN - 1);
  const int tid = threadIdx.x, c0 = tid * 8;
  const int hq = tid >> 1, j0 = (tid & 1) * 8;
  const char* pb = packed + (size_t)((bq * 128 + hq) * T_LEN + tq) * REC;
  float rv[8], kv[8], vv[8];
  u32x4 pk0 = *(const u32x4*)(pb + j0 * 8);
  u32x4 pk1 = *(const u32x4*)(pb + j0 * 8 + 16);
  u32x4 pk2 = *(const u32x4*)(pb + j0 * 8 + 32);
  u32x4 pk3 = *(const u32x4*)(pb + j0 * 8 + 48);
  kv[0] = bflo(pk0[1]); rv[0] = bfhi(pk0[1]); kv[1] = bflo(pk0[3]); rv[1] = bfhi(pk0[3]);
  kv[2] = bflo(pk1[1]); rv[2] = bfhi(pk1[1]); kv[3] = bflo(pk1[3]); rv[3] = bfhi(pk1[3]);
  kv[4] = bflo(pk2[1]); rv[4] = bfhi(pk2[1]); kv[5] = bflo(pk2[3]); rv[5] = bfhi(pk2[3]);
  kv[6] = bflo(pk3[1]); rv[6] = bfhi(pk3[1]); kv[7] = bflo(pk3[3]); rv[7] = bfhi(pk3[3]);
  u32x4 uv = *(const u32x4*)(pb + 192 + 2 * j0);
  #pragma unroll
  for (int ii = 0; ii < 4; ++ii) {
    vv[2 * ii] = bflo(uv[ii]); vv[2 * ii + 1] = bfhi(uv[ii]);
  }
  f32x4 y0 = *(const f32x4*)(pb + 128 + 4 * j0);
  f32x4 y1 = *(const f32x4*)(pb + 128 + 4 * j0 + 16);
  float o[8];
  o[0] = y0[0]; o[1] = y0[1]; o[2] = y0[2]; o[3] = y0[3];
  o[4] = y1[0]; o[5] = y1[1]; o[6] = y1[2]; o[7] = y1[3];
  float g8[8] __attribute__((aligned(16)));
  const float* lo = lora8 + (size_t)rr * 32 + 24;
  *(f32x4*)g8 = *(const f32x4*)lo;
  *(f32x4*)(g8 + 4) = *(const f32x4*)(lo + 4);
  // vectorized gate projection accumulation
  float gg8[8] __attribute__((aligned(16)));
  #pragma unroll
  for (int ii = 0; ii < 8; ++ii) gg8[ii] = 0.f;
  #pragma unroll
  for (int l = 0; l < 8; ++l) {
    float tg[8] __attribute__((aligned(16)));
    *(f32x4*)tg = *(const f32x4*)(g2 + (size_t)l * C_DIM + c0);
    *(f32x4*)(tg + 4) = *(const f32x4*)(g2 + (size_t)l * C_DIM + c0 + 4);
    #pragma unroll
    for (int ii = 0; ii < 8; ++ii) gg8[ii] = fmaf(g8[l], tg[ii], gg8[ii]);
  }
  float rk8[8] __attribute__((aligned(16)));
  float lg8[8] __attribute__((aligned(16)));
  float lb8[8] __attribute__((aligned(16)));
  *(f32x4*)rk8 = *(const f32x4*)(r_k + c0); *(f32x4*)(rk8 + 4) = *(const f32x4*)(r_k + c0 + 4);
  *(f32x4*)lg8 = *(const f32x4*)(ln_g + c0); *(f32x4*)(lg8 + 4) = *(const f32x4*)(ln_g + c0 + 4);
  *(f32x4*)lb8 = *(const f32x4*)(ln_b + c0); *(f32x4*)(lb8 + 4) = *(const f32x4*)(ln_b + c0 + 4);
  float s1 = 0.f, s2 = 0.f, srk = 0.f;
  #pragma unroll
  for (int ii = 0; ii < 8; ++ii) {
    s1 += o[ii];
    s2 = fmaf(o[ii], o[ii], s2);
    srk = fmaf(rv[ii] * kv[ii], rk8[ii], srk);
  }
  s1 += __shfl_xor(s1, 1); s1 += __shfl_xor(s1, 2); s1 += __shfl_xor(s1, 4);
  s2 += __shfl_xor(s2, 1); s2 += __shfl_xor(s2, 2); s2 += __shfl_xor(s2, 4);
  srk += __shfl_xor(srk, 1); srk += __shfl_xor(srk, 2); srk += __shfl_xor(srk, 4);
  float mu = s1 * (1.f / 64.f);
  float var = s2 * (1.f / 64.f) - mu * mu;
  float rstd = rsqrtf(var + 0.00064f);
  u16x8 ov;
  #pragma unroll
  for (int ii = 0; ii < 8; ++ii) {
    float on = fmaf((o[ii] - mu) * rstd, lg8[ii], lb8[ii]);
    float o2 = fmaf(srk, vv[ii], on);
    ov[ii] = f2bf(o2 * gg8[ii]);
  }
  *(u16x8*)(og + (size_t)rr * C_DIM + c0) = ov;
}

extern "C" void kernel_launch(void* const* d_in, const int* in_sizes, int n_in,
                              void* d_out, int out_size, void* d_ws, size_t ws_size,
                              hipStream_t stream) {
  (void)in_sizes; (void)n_in; (void)out_size;
  const float* x      = (const float*)d_in[0];
  const float* v_first= (const float*)d_in[1];
  const float* x_r    = (const float*)d_in[2];
  const float* x_w    = (const float*)d_in[3];
  const float* x_k    = (const float*)d_in[4];
  const float* x_v    = (const float*)d_in[5];
  const float* x_a    = (const float*)d_in[6];
  const float* x_g    = (const float*)d_in[7];
  const float* w0     = (const float*)d_in[8];
  const float* w1     = (const float*)d_in[9];
  const float* w2     = (const float*)d_in[10];
  const float* a0     = (const float*)d_in[11];
  const float* a1     = (const float*)d_in[12];
  const float* a2     = (const float*)d_in[13];
  const float* v0     = (const float*)d_in[14];
  const float* v1     = (const float*)d_in[15];
  const float* v2     = (const float*)d_in[16];
  const float* g1     = (const float*)d_in[17];
  const float* g2     = (const float*)d_in[18];
  const float* k_k    = (const float*)d_in[19];
  const float* k_a    = (const float*)d_in[20];
  const float* r_k    = (const float*)d_in[21];
  const float* Wr     = (const float*)d_in[22];
  const float* Wk     = (const float*)d_in[23];
  const float* Wv     = (const float*)d_in[24];
  const float* Wo     = (const float*)d_in[25];
  const float* ln_g   = (const float*)d_in[26];
  const float* ln_b   = (const float*)d_in[27];

  if (ws_size < 370147328ull) return;
  char* ws = (char*)d_ws;
  u16* Wr_bf = (u16*)(ws + 0);            //  8 MB each, contiguous (conv indexes)
  u16* Wk_bf = Wr_bf + 4194304;
  u16* Wv_bf = Wk_bf + 4194304;
  u16* Wo_bf = Wv_bf + 4194304;
  u16* xr_bf = (u16*)(ws + 33554432);     // 32 MB each
  u16* xk_bf = xr_bf + 16777216;
  u16* xv_bf = xk_bf + 16777216;
  float* lora8 = (float*)(ws + 134217728); // 1 MB
  char* packed = ws + 135266304;           // 224 MB
  float* wt = (float*)packed;              // transposed LoRA tables (256 KB),
                                           // consumed before gemms overwrite
  u16* og = xr_bf;                         // reuse (dead after r-GEMM)
  float* out = (float*)d_out;

  // allow 128 KB dynamic LDS for the GEMM (idempotent; harmless if no-op)
  (void)hipFuncSetAttribute((const void*)gemm8_k,
                            hipFuncAttributeMaxDynamicSharedMemorySize, 131072);

  conv_bf16_k<<<dim3(2048, 4), 256, 0, stream>>>(Wr, Wk, Wv, Wo, Wr_bf);
  trans_lora_k<<<dim3(8, 4), 256, 0, stream>>>(w1, a1, v1, g1, wt);

  mix_lora_k<<<8192, 256, 0, stream>>>(x, x_r, x_w, x_k, x_v, x_a, x_g,
                                       wt, xr_bf, xk_bf, xv_bf, lora8);

  gemm8_k<<<dim3(8, 32, 3), 512, 131072, stream>>>(xk_bf, xr_bf, xv_bf,
                                                   Wk_bf, Wr_bf, Wv_bf,
                                                   packed, 1);

  post_gemm_k<<<8192, 256, 0, stream>>>(v_first, lora8, w0, w2, a0, a2, v0, v2,
                                        k_k, k_a, packed);

  scan_k<<<256, 256, 0, stream>>>(packed);

  post_gn_k<<<8192, 256, 0, stream>>>(packed, lora8, g2, ln_g, ln_b, r_k, og);

  gemm8_k<<<dim3(8, 32, 1), 512, 131072, stream>>>(og, og, og,
                                                   Wo_bf, Wo_bf, Wo_bf,
                                                   (char*)out, 0);

  hipMemcpyAsync(out + 16777216, v_first, (size_t)16777216 * 4,
                 hipMemcpyDeviceToDevice, stream);
}